// Round 3
// baseline (906.324 us; speedup 1.0000x reference)
//
#include <hip/hip_runtime.h>

// ---------------------------------------------------------------------------
// EntropyCalculator: 2-layer post-norm transformer encoder + entropy head.
// B=256 S=512 D=128 H=4 HD=32 FF=512 V=256
// ---------------------------------------------------------------------------

#define AS1 __attribute__((address_space(1)))
#define AS3 __attribute__((address_space(3)))

typedef __bf16 bf16x8 __attribute__((ext_vector_type(8)));
typedef __bf16 bf16x4 __attribute__((ext_vector_type(4)));
typedef float  f32x4  __attribute__((ext_vector_type(4)));

__device__ __forceinline__ unsigned short f2bf(float f) {
  union { float f; unsigned int u; } c; c.f = f;
  unsigned int u = c.u;
  u += 0x7FFFu + ((u >> 16) & 1u);   // round-to-nearest-even
  return (unsigned short)(u >> 16);
}

__device__ __forceinline__ void async_copy16(const void* g, void* l) {
  __builtin_amdgcn_global_load_lds((AS1 void*)(void*)g, (AS3 void*)l, 16, 0, 0);
}

__device__ __forceinline__ unsigned int cvtpk_bf16(float lo, float hi) {
  unsigned int r;
  asm("v_cvt_pk_bf16_f32 %0, %1, %2" : "=v"(r) : "v"(lo), "v"(hi));
  return r;
}
__device__ __forceinline__ void plswap32(unsigned int& a, unsigned int& b) {
  asm("v_permlane32_swap_b32 %0, %1" : "+v"(a), "+v"(b));
}
__device__ __forceinline__ void plswap16(unsigned int& a, unsigned int& b) {
  asm("v_permlane16_swap_b32 %0, %1" : "+v"(a), "+v"(b));
}

// ---------------------------------------------------------------------------
__global__ void f32_to_bf16(const float* __restrict__ src,
                            unsigned short* __restrict__ dst, int n) {
  int i = blockIdx.x * blockDim.x + threadIdx.x;
  if (i < n) dst[i] = f2bf(src[i]);
}

// ---------------------------------------------------------------------------
// Embedding + LayerNorm.  One wave per token.
// ---------------------------------------------------------------------------
__global__ __launch_bounds__(256) void embed_ln(
    const int* __restrict__ bytes, const float* __restrict__ emb,
    const float* __restrict__ pos, const float* __restrict__ g,
    const float* __restrict__ bta, float* __restrict__ h,
    unsigned short* __restrict__ hbf) {
  int wv = threadIdx.x >> 6, lane = threadIdx.x & 63;
  int tok = blockIdx.x * 4 + wv;
  int s = tok & 511;
  int bidx = bytes[tok];
  const float* e = emb + (size_t)bidx * 128;
  const float* p = pos + (size_t)s * 128;
  float x0 = e[lane] + p[lane];
  float x1 = e[lane + 64] + p[lane + 64];
  float sum = x0 + x1, ssq = x0 * x0 + x1 * x1;
#pragma unroll
  for (int off = 32; off; off >>= 1) {
    sum += __shfl_xor(sum, off);
    ssq += __shfl_xor(ssq, off);
  }
  float mean = sum * 0.0078125f;
  float var = ssq * 0.0078125f - mean * mean;
  float rs = rsqrtf(var + 1e-5f);
  float y0 = (x0 - mean) * rs * g[lane] + bta[lane];
  float y1 = (x1 - mean) * rs * g[lane + 64] + bta[lane + 64];
  size_t o = (size_t)tok * 128;
  h[o + lane] = y0; h[o + lane + 64] = y1;
  hbf[o + lane] = f2bf(y0); hbf[o + lane + 64] = f2bf(y1);
}

// ---------------------------------------------------------------------------
// Residual + LayerNorm (in place on h), also writes bf16 copy.
// ---------------------------------------------------------------------------
__global__ __launch_bounds__(256) void ln_res(
    float* h, const float* __restrict__ r, const float* __restrict__ g,
    const float* __restrict__ bta, unsigned short* __restrict__ hbf) {
  int wv = threadIdx.x >> 6, lane = threadIdx.x & 63;
  int tok = blockIdx.x * 4 + wv;
  size_t o = (size_t)tok * 128;
  float x0 = h[o + lane] + r[o + lane];
  float x1 = h[o + lane + 64] + r[o + lane + 64];
  float sum = x0 + x1, ssq = x0 * x0 + x1 * x1;
#pragma unroll
  for (int off = 32; off; off >>= 1) {
    sum += __shfl_xor(sum, off);
    ssq += __shfl_xor(ssq, off);
  }
  float mean = sum * 0.0078125f;
  float var = ssq * 0.0078125f - mean * mean;
  float rs = rsqrtf(var + 1e-5f);
  float y0 = (x0 - mean) * rs * g[lane] + bta[lane];
  float y1 = (x1 - mean) * rs * g[lane + 64] + bta[lane + 64];
  h[o + lane] = y0; h[o + lane + 64] = y1;
  hbf[o + lane] = f2bf(y0); hbf[o + lane + 64] = f2bf(y1);
}

// ---------------------------------------------------------------------------
// bf16 MFMA GEMM:  C[M,N] = A[M,K] @ W[N,K]^T + bias
// 128x128 tile, BK=64, 4 waves, each wave 64x64 via 4x4 frags of 16x16x32.
// ---------------------------------------------------------------------------
template <int RELU, int OUTBF>
__global__ __launch_bounds__(256) void gemm_bf16(
    const unsigned short* __restrict__ A, const unsigned short* __restrict__ W,
    const float* __restrict__ bias, void* __restrict__ Cout,
    int M, int N, int K) {
  __shared__ __bf16 As[128 * 64];
  __shared__ __bf16 Ws[128 * 64];
  const int t = threadIdx.x;
  const int lane = t & 63, w = t >> 6;
  const int m0 = blockIdx.y * 128, n0 = blockIdx.x * 128;
  const int wm = (w >> 1) * 64, wn = (w & 1) * 64;
  f32x4 acc[4][4] = {};
  const int srow = w * 32 + (lane >> 3);
  const int scol = (lane & 7) * 8;

  for (int k0 = 0; k0 < K; k0 += 64) {
#pragma unroll
    for (int j = 0; j < 4; ++j) {
      int r = srow + j * 8;
      int ldsrow = w * 32 + j * 8;
      async_copy16(A + (size_t)(m0 + r) * K + k0 + scol, &As[ldsrow * 64]);
      async_copy16(W + (size_t)(n0 + r) * K + k0 + scol, &Ws[ldsrow * 64]);
    }
    __syncthreads();
#pragma unroll
    for (int kk = 0; kk < 2; ++kk) {
      bf16x8 af[4], bfr[4];
#pragma unroll
      for (int f = 0; f < 4; ++f) {
        af[f]  = *(const bf16x8*)&As[(wm + f * 16 + (lane & 15)) * 64 + kk * 32 + (lane >> 4) * 8];
        bfr[f] = *(const bf16x8*)&Ws[(wn + f * 16 + (lane & 15)) * 64 + kk * 32 + (lane >> 4) * 8];
      }
#pragma unroll
      for (int fi = 0; fi < 4; ++fi)
#pragma unroll
        for (int fj = 0; fj < 4; ++fj)
          acc[fi][fj] = __builtin_amdgcn_mfma_f32_16x16x32_bf16(
              af[fi], bfr[fj], acc[fi][fj], 0, 0, 0);
    }
    __syncthreads();
  }

#pragma unroll
  for (int fj = 0; fj < 4; ++fj) {
    int col = n0 + wn + fj * 16 + (lane & 15);
    float bv = bias[col];
#pragma unroll
    for (int fi = 0; fi < 4; ++fi) {
#pragma unroll
      for (int r2 = 0; r2 < 4; ++r2) {
        int row = m0 + wm + fi * 16 + (lane >> 4) * 4 + r2;
        float v = acc[fi][fj][r2] + bv;
        if (RELU) v = fmaxf(v, 0.0f);
        if (OUTBF)
          ((unsigned short*)Cout)[(size_t)row * N + col] = f2bf(v);
        else
          ((float*)Cout)[(size_t)row * N + col] = v;
      }
    }
  }
}

// ---------------------------------------------------------------------------
// MFMA flash attention, register-resident P (no P LDS, no in-loop barriers).
// One block (512 thr = 8 waves) per (batch, head).  Wave owns 64 queries.
// QK^T: S^T = mfma(K_frag, Q_frag) -> lane(c,g) holds P[q=c][key kf*16+g*4+r].
// P redistribution to PV B-operand (lane(c,g) needs P[q=c][keys g*8+j]) via
// cvt_pk_bf16 + permlane32_swap + permlane16_swap (pure VALU, verified map).
// PV: O^T = mfma(Vt_frag(A), P^T_frag(B)) -> lane holds O[q=c][d=g*4+r],
// so 1/l scale is lane-local and stores are 8B-packed.
// LDS: Ks[512][40] + Vt[32][520] = 74240 B -> 2 blocks/CU.
// ---------------------------------------------------------------------------
__global__ __launch_bounds__(512, 4) void attn_mfma(
    const unsigned short* __restrict__ qkv, unsigned short* __restrict__ obf) {
  __shared__ __bf16 Ks[512 * 40];
  __shared__ __bf16 Vt[32 * 520];

  const int hh = blockIdx.x & 3, bl = blockIdx.x >> 2;
  const int t = threadIdx.x;
  const int lane = t & 63, wv = t >> 6;
  const int c = lane & 15, g = lane >> 4;
  const size_t tok0 = (size_t)bl * 512;

  // ---- stage K rows and V^T ----
  {
    const unsigned short* kr = qkv + (tok0 + t) * 384 + 128 + hh * 32;
    bf16x8 k0 = *(const bf16x8*)(kr);
    bf16x8 k1 = *(const bf16x8*)(kr + 8);
    bf16x8 k2 = *(const bf16x8*)(kr + 16);
    bf16x8 k3 = *(const bf16x8*)(kr + 24);
    __bf16* kd = Ks + t * 40;
    *(bf16x8*)(kd + 0) = k0;  *(bf16x8*)(kd + 8) = k1;
    *(bf16x8*)(kd + 16) = k2; *(bf16x8*)(kd + 24) = k3;
    const unsigned short* vr = kr + 128;
    bf16x8 v0 = *(const bf16x8*)(vr);
    bf16x8 v1 = *(const bf16x8*)(vr + 8);
    bf16x8 v2 = *(const bf16x8*)(vr + 16);
    bf16x8 v3 = *(const bf16x8*)(vr + 24);
#pragma unroll
    for (int i = 0; i < 8; ++i) {
      Vt[(i)      * 520 + t] = v0[i];
      Vt[(i + 8)  * 520 + t] = v1[i];
      Vt[(i + 16) * 520 + t] = v2[i];
      Vt[(i + 24) * 520 + t] = v3[i];
    }
  }

  // ---- Q fragments (B-operand): lane holds Q[qf*16+c][g*8 .. g*8+7] ----
  bf16x8 qb[4];
  {
    const unsigned short* qp = qkv + (tok0 + wv * 64) * 384 + hh * 32;
#pragma unroll
    for (int qf = 0; qf < 4; ++qf)
      qb[qf] = *(const bf16x8*)(qp + (size_t)(qf * 16 + c) * 384 + g * 8);
  }
  __syncthreads();

  f32x4 ot[4][2] = {};                 // O^T accum: [qf][hf], q=c, d=g*4+r
  float l[4] = {0.f, 0.f, 0.f, 0.f};
  const float C = 0.17677669529663687f * 1.4426950408889634f;  // scale*log2e
  const f32x4 zz = {0.f, 0.f, 0.f, 0.f};

  for (int kt = 0; kt < 8; ++kt) {
    bf16x8 ka[4];
#pragma unroll
    for (int kf = 0; kf < 4; ++kf)
      ka[kf] = *(const bf16x8*)&Ks[(kt * 64 + kf * 16 + c) * 40 + g * 8];
    bf16x8 vb[2][2];
#pragma unroll
    for (int hf = 0; hf < 2; ++hf)
#pragma unroll
      for (int ksl = 0; ksl < 2; ++ksl)
        vb[hf][ksl] =
            *(const bf16x8*)&Vt[(hf * 16 + c) * 520 + kt * 64 + ksl * 32 + g * 8];

#pragma unroll
    for (int qf = 0; qf < 4; ++qf) {
      f32x4 sA = __builtin_amdgcn_mfma_f32_16x16x32_bf16(ka[0], qb[qf], zz, 0, 0, 0);
      f32x4 sB = __builtin_amdgcn_mfma_f32_16x16x32_bf16(ka[1], qb[qf], zz, 0, 0, 0);
      f32x4 sC = __builtin_amdgcn_mfma_f32_16x16x32_bf16(ka[2], qb[qf], zz, 0, 0, 0);
      f32x4 sD = __builtin_amdgcn_mfma_f32_16x16x32_bf16(ka[3], qb[qf], zz, 0, 0, 0);

      // ksl = 0  (kf 0,1)
      {
        float pa0 = exp2f(sA[0] * C), pa1 = exp2f(sA[1] * C);
        float pa2 = exp2f(sA[2] * C), pa3 = exp2f(sA[3] * C);
        float pb0 = exp2f(sB[0] * C), pb1 = exp2f(sB[1] * C);
        float pb2 = exp2f(sB[2] * C), pb3 = exp2f(sB[3] * C);
        l[qf] += (pa0 + pa1) + (pa2 + pa3) + (pb0 + pb1) + (pb2 + pb3);
        unsigned int w00 = cvtpk_bf16(pa0, pa1), w01 = cvtpk_bf16(pa2, pa3);
        unsigned int w10 = cvtpk_bf16(pb0, pb1), w11 = cvtpk_bf16(pb2, pb3);
        plswap32(w00, w10); plswap16(w00, w10);   // w00=jw0, w10=jw2
        plswap32(w01, w11); plswap16(w01, w11);   // w01=jw1, w11=jw3
        union { unsigned int u[4]; bf16x8 v; } pk;
        pk.u[0] = w00; pk.u[1] = w01; pk.u[2] = w10; pk.u[3] = w11;
        ot[qf][0] = __builtin_amdgcn_mfma_f32_16x16x32_bf16(vb[0][0], pk.v,
                                                            ot[qf][0], 0, 0, 0);
        ot[qf][1] = __builtin_amdgcn_mfma_f32_16x16x32_bf16(vb[1][0], pk.v,
                                                            ot[qf][1], 0, 0, 0);
      }
      // ksl = 1  (kf 2,3)
      {
        float pa0 = exp2f(sC[0] * C), pa1 = exp2f(sC[1] * C);
        float pa2 = exp2f(sC[2] * C), pa3 = exp2f(sC[3] * C);
        float pb0 = exp2f(sD[0] * C), pb1 = exp2f(sD[1] * C);
        float pb2 = exp2f(sD[2] * C), pb3 = exp2f(sD[3] * C);
        l[qf] += (pa0 + pa1) + (pa2 + pa3) + (pb0 + pb1) + (pb2 + pb3);
        unsigned int w00 = cvtpk_bf16(pa0, pa1), w01 = cvtpk_bf16(pa2, pa3);
        unsigned int w10 = cvtpk_bf16(pb0, pb1), w11 = cvtpk_bf16(pb2, pb3);
        plswap32(w00, w10); plswap16(w00, w10);
        plswap32(w01, w11); plswap16(w01, w11);
        union { unsigned int u[4]; bf16x8 v; } pk;
        pk.u[0] = w00; pk.u[1] = w01; pk.u[2] = w10; pk.u[3] = w11;
        ot[qf][0] = __builtin_amdgcn_mfma_f32_16x16x32_bf16(vb[0][1], pk.v,
                                                            ot[qf][0], 0, 0, 0);
        ot[qf][1] = __builtin_amdgcn_mfma_f32_16x16x32_bf16(vb[1][1], pk.v,
                                                            ot[qf][1], 0, 0, 0);
      }
    }
  }

#pragma unroll
  for (int qf = 0; qf < 4; ++qf) {
    l[qf] += __shfl_xor(l[qf], 16);
    l[qf] += __shfl_xor(l[qf], 32);
  }
  // lane(c,g) holds O[q = wv*64+qf*16+c][d = hh*32 + hf*16 + g*4 + r]
#pragma unroll
  for (int qf = 0; qf < 4; ++qf) {
    float rl = 1.0f / l[qf];
#pragma unroll
    for (int hf = 0; hf < 2; ++hf) {
      ushort4 pk;
      pk.x = f2bf(ot[qf][hf][0] * rl);
      pk.y = f2bf(ot[qf][hf][1] * rl);
      pk.z = f2bf(ot[qf][hf][2] * rl);
      pk.w = f2bf(ot[qf][hf][3] * rl);
      *(ushort4*)(obf + (tok0 + wv * 64 + qf * 16 + c) * 128 + hh * 32 +
                  hf * 16 + g * 4) = pk;
    }
  }
}

// ---------------------------------------------------------------------------
// Entropy from logits chunk [ntok][256].  One wave per token.
// ---------------------------------------------------------------------------
__global__ __launch_bounds__(256) void entropy_from_logits(
    const float* __restrict__ logits, float* __restrict__ ent) {
  int wv = threadIdx.x >> 6, lane = threadIdx.x & 63;
  int tok = blockIdx.x * 4 + wv;
  const float* lp = logits + (size_t)tok * 256;
  float4 x = *(const float4*)(lp + lane * 4);
  float m = fmaxf(fmaxf(x.x, x.y), fmaxf(x.z, x.w));
#pragma unroll
  for (int off = 32; off; off >>= 1) m = fmaxf(m, __shfl_xor(m, off));
  float e0 = __expf(x.x - m), e1 = __expf(x.y - m);
  float e2 = __expf(x.z - m), e3 = __expf(x.w - m);
  float z = e0 + e1 + e2 + e3;
  float sx = e0 * x.x + e1 * x.y + e2 * x.z + e3 * x.w;
#pragma unroll
  for (int off = 32; off; off >>= 1) {
    z += __shfl_xor(z, off);
    sx += __shfl_xor(sx, off);
  }
  if (lane == 0) ent[tok] = m + logf(z) - sx / z;
}

__global__ __launch_bounds__(64) void avg_entropy_kernel(
    const float* __restrict__ ent, float* __restrict__ out) {
  int s = blockIdx.x, lane = threadIdx.x;
  float a = 0.f;
  for (int b = lane; b < 256; b += 64) a += ent[(size_t)b * 512 + s];
#pragma unroll
  for (int off = 32; off; off >>= 1) a += __shfl_xor(a, off);
  if (lane == 0) out[s] = a * 0.00390625f;
}

__global__ __launch_bounds__(512) void seg_kernel(float* out) {
  __shared__ int cs[512];
  int i = threadIdx.x;
  float e = out[i];
  cs[i] = (i >= 1 && e > 4.0f) ? 1 : 0;
  __syncthreads();
  for (int off = 1; off < 512; off <<= 1) {
    int v = (i >= off) ? cs[i - off] : 0;
    __syncthreads();
    cs[i] += v;
    __syncthreads();
  }
  out[512 + i] = (float)cs[i];
}

// ---------------------------------------------------------------------------
extern "C" void kernel_launch(void* const* d_in, const int* in_sizes, int n_in,
                              void* d_out, int out_size, void* d_ws,
                              size_t ws_size, hipStream_t stream) {
  (void)in_sizes; (void)n_in; (void)out_size; (void)ws_size;
  const int*   input_bytes = (const int*)d_in[0];
  const float* emb    = (const float*)d_in[1];
  const float* pos    = (const float*)d_in[2];
  const float* ln_g   = (const float*)d_in[3];
  const float* ln_b   = (const float*)d_in[4];
  const float* attn_w = (const float*)d_in[5];
  const float* attn_b = (const float*)d_in[6];
  const float* out_w  = (const float*)d_in[7];
  const float* out_b  = (const float*)d_in[8];
  const float* ff1_w  = (const float*)d_in[9];
  const float* ff1_b  = (const float*)d_in[10];
  const float* ff2_w  = (const float*)d_in[11];
  const float* ff2_b  = (const float*)d_in[12];
  const float* n1_g   = (const float*)d_in[13];
  const float* n1_b   = (const float*)d_in[14];
  const float* n2_g   = (const float*)d_in[15];
  const float* n2_b   = (const float*)d_in[16];
  const float* proj_w = (const float*)d_in[17];
  const float* proj_b = (const float*)d_in[18];

  char* ws = (char*)d_ws;
  float*          h      = (float*)(ws);                      // 64 MB
  unsigned short* hbf    = (unsigned short*)(ws + 67108864);  // 32 MB
  char*           Cr     = ws + 100663296;                    // 98 MB scratch
  unsigned short* obf    = (unsigned short*)Cr;               // 32 MB
  unsigned short* qkvc   = (unsigned short*)(Cr + 33554432);  // 50.3 MB (attn)
  float*          s1     = (float*)(Cr + 33554432);           // 64 MB (post)
  unsigned short* ff1t   = (unsigned short*)Cr;               // 33.5 MB (ffn)
  float*          logits = (float*)Cr;                        // 33.5 MB (final)
  unsigned short* wbf    = (unsigned short*)(ws + 203423744);
  float*          entb   = (float*)(ws + 204283904);          // 0.5 MB

  unsigned short* attnw_bf = wbf;
  unsigned short* outw_bf  = wbf + 98304;
  unsigned short* ff1_bf   = wbf + 131072;
  unsigned short* ff2_bf   = wbf + 262144;
  unsigned short* projw_bf = wbf + 393216;

  f32_to_bf16<<<384, 256, 0, stream>>>(attn_w, attnw_bf, 98304);
  f32_to_bf16<<<128, 256, 0, stream>>>(out_w, outw_bf, 32768);
  f32_to_bf16<<<512, 256, 0, stream>>>(ff1_w, ff1_bf, 131072);
  f32_to_bf16<<<512, 256, 0, stream>>>(ff2_w, ff2_bf, 131072);
  f32_to_bf16<<<128, 256, 0, stream>>>(proj_w, projw_bf, 32768);

  embed_ln<<<32768, 256, 0, stream>>>(input_bytes, emb, pos, ln_g, ln_b, h, hbf);

  for (int l = 0; l < 2; ++l) {
    // QKV GEMM (bf16 out) + MFMA attention, 2 batch-chunks of 128 batches
    for (int ch = 0; ch < 2; ++ch) {
      gemm_bf16<0, 1><<<dim3(3, 512), 256, 0, stream>>>(
          hbf + (size_t)ch * 65536 * 128, attnw_bf + l * 49152,
          attn_b + l * 384, qkvc, 65536, 384, 128);
      attn_mfma<<<512, 512, 0, stream>>>(qkvc,
                                         obf + (size_t)ch * 65536 * 128);
    }
    // output projection over all tokens (f32 out for residual)
    gemm_bf16<0, 0><<<dim3(1, 1024), 256, 0, stream>>>(
        obf, outw_bf + l * 16384, out_b + l * 128, s1, 131072, 128, 128);
    ln_res<<<32768, 256, 0, stream>>>(h, s1, n1_g + l * 128, n1_b + l * 128, hbf);
    // FFN in 4 token-chunks of 32768
    for (int tc = 0; tc < 4; ++tc) {
      gemm_bf16<1, 1><<<dim3(4, 256), 256, 0, stream>>>(
          hbf + (size_t)tc * 32768 * 128, ff1_bf + l * 65536,
          ff1_b + l * 512, ff1t, 32768, 512, 128);
      gemm_bf16<0, 0><<<dim3(1, 256), 256, 0, stream>>>(
          ff1t, ff2_bf + l * 65536, ff2_b + l * 128,
          s1 + (size_t)tc * 32768 * 128, 32768, 128, 512);
    }
    ln_res<<<32768, 256, 0, stream>>>(h, s1, n2_g + l * 128, n2_b + l * 128, hbf);
  }

  // vocab projection + entropy, 4 token-chunks
  for (int tc = 0; tc < 4; ++tc) {
    gemm_bf16<0, 0><<<dim3(2, 256), 256, 0, stream>>>(
        hbf + (size_t)tc * 32768 * 128, projw_bf, proj_b, logits, 32768, 256, 128);
    entropy_from_logits<<<8192, 256, 0, stream>>>(logits,
                                                  entb + (size_t)tc * 32768);
  }
  avg_entropy_kernel<<<512, 64, 0, stream>>>(entb, (float*)d_out);
  seg_kernel<<<1, 512, 0, stream>>>((float*)d_out);
}

// Round 4
// 693.416 us; speedup vs baseline: 1.3070x; 1.3070x over previous
//
#include <hip/hip_runtime.h>

// ---------------------------------------------------------------------------
// EntropyCalculator: 2-layer post-norm transformer encoder + entropy head.
// B=256 S=512 D=128 H=4 HD=32 FF=512 V=256
// bf16 residual stream (hbf); fused GEMM+LN and GEMM+entropy epilogues.
// ---------------------------------------------------------------------------

#define AS1 __attribute__((address_space(1)))
#define AS3 __attribute__((address_space(3)))

typedef __bf16 bf16x8 __attribute__((ext_vector_type(8)));
typedef __bf16 bf16x4 __attribute__((ext_vector_type(4)));
typedef float  f32x4  __attribute__((ext_vector_type(4)));

__device__ __forceinline__ unsigned short f2bf(float f) {
  union { float f; unsigned int u; } c; c.f = f;
  unsigned int u = c.u;
  u += 0x7FFFu + ((u >> 16) & 1u);   // round-to-nearest-even
  return (unsigned short)(u >> 16);
}
__device__ __forceinline__ float bf2f(unsigned short u) {
  union { unsigned int u; float f; } c; c.u = ((unsigned int)u) << 16;
  return c.f;
}

__device__ __forceinline__ float EXP2(float x) {
#if __has_builtin(__builtin_amdgcn_exp2f)
  return __builtin_amdgcn_exp2f(x);
#else
  return exp2f(x);
#endif
}

__device__ __forceinline__ void async_copy16(const void* g, void* l) {
  __builtin_amdgcn_global_load_lds((AS1 void*)(void*)g, (AS3 void*)l, 16, 0, 0);
}

__device__ __forceinline__ unsigned int cvtpk_bf16(float lo, float hi) {
  unsigned int r;
  asm("v_cvt_pk_bf16_f32 %0, %1, %2" : "=v"(r) : "v"(lo), "v"(hi));
  return r;
}
__device__ __forceinline__ void plswap32(unsigned int& a, unsigned int& b) {
  asm("v_permlane32_swap_b32 %0, %1" : "+v"(a), "+v"(b));
}
__device__ __forceinline__ void plswap16(unsigned int& a, unsigned int& b) {
  asm("v_permlane16_swap_b32 %0, %1" : "+v"(a), "+v"(b));
}

// ---------------------------------------------------------------------------
// weight conversions
// ---------------------------------------------------------------------------
__global__ void f32_to_bf16(const float* __restrict__ src,
                            unsigned short* __restrict__ dst, int n) {
  int i = blockIdx.x * blockDim.x + threadIdx.x;
  if (i < n) dst[i] = f2bf(src[i]);
}

// attn_w with Q rows pre-scaled by (1/sqrt(HD))*log2(e)
#define QSCALE 0.2550602989892646f
__global__ void conv_attn_w(const float* __restrict__ src,
                            unsigned short* __restrict__ dst) {
  int i = blockIdx.x * 256 + threadIdx.x;  // 98304
  int r = (i >> 7) % 384;
  float v = src[i];
  if (r < 128) v *= QSCALE;
  dst[i] = f2bf(v);
}
__global__ void conv_attn_b(const float* __restrict__ src,
                            float* __restrict__ dst) {
  int i = blockIdx.x * 256 + threadIdx.x;  // 768
  if (i < 768) {
    float v = src[i];
    if ((i % 384) < 128) v *= QSCALE;
    dst[i] = v;
  }
}

// ---------------------------------------------------------------------------
// Embedding + LayerNorm -> bf16 residual stream.  One wave per token.
// ---------------------------------------------------------------------------
__global__ __launch_bounds__(256) void embed_ln(
    const int* __restrict__ bytes, const float* __restrict__ emb,
    const float* __restrict__ pos, const float* __restrict__ g,
    const float* __restrict__ bta, unsigned short* __restrict__ hbf) {
  int wv = threadIdx.x >> 6, lane = threadIdx.x & 63;
  int tok = blockIdx.x * 4 + wv;
  int s = tok & 511;
  int bidx = bytes[tok];
  const float* e = emb + (size_t)bidx * 128;
  const float* p = pos + (size_t)s * 128;
  float x0 = e[lane] + p[lane];
  float x1 = e[lane + 64] + p[lane + 64];
  float sum = x0 + x1, ssq = x0 * x0 + x1 * x1;
#pragma unroll
  for (int off = 32; off; off >>= 1) {
    sum += __shfl_xor(sum, off);
    ssq += __shfl_xor(ssq, off);
  }
  float mean = sum * 0.0078125f;
  float var = ssq * 0.0078125f - mean * mean;
  float rs = rsqrtf(var + 1e-5f);
  float y0 = (x0 - mean) * rs * g[lane] + bta[lane];
  float y1 = (x1 - mean) * rs * g[lane + 64] + bta[lane + 64];
  size_t o = (size_t)tok * 128;
  hbf[o + lane] = f2bf(y0); hbf[o + lane + 64] = f2bf(y1);
}

// ---------------------------------------------------------------------------
// bf16 MFMA GEMM:  C[M,N] = A[M,K] @ W[N,K]^T + bias  (plain / relu / bf16out)
// 128x128 tile, BK=64, 4 waves.
// ---------------------------------------------------------------------------
template <int RELU, int OUTBF>
__global__ __launch_bounds__(256) void gemm_bf16(
    const unsigned short* __restrict__ A, const unsigned short* __restrict__ W,
    const float* __restrict__ bias, void* __restrict__ Cout,
    int M, int N, int K) {
  __shared__ __bf16 As[128 * 64];
  __shared__ __bf16 Ws[128 * 64];
  const int t = threadIdx.x;
  const int lane = t & 63, w = t >> 6;
  const int m0 = blockIdx.y * 128, n0 = blockIdx.x * 128;
  const int wm = (w >> 1) * 64, wn = (w & 1) * 64;
  f32x4 acc[4][4] = {};
  const int srow = w * 32 + (lane >> 3);
  const int scol = (lane & 7) * 8;

  for (int k0 = 0; k0 < K; k0 += 64) {
#pragma unroll
    for (int j = 0; j < 4; ++j) {
      int r = srow + j * 8;
      int ldsrow = w * 32 + j * 8;
      async_copy16(A + (size_t)(m0 + r) * K + k0 + scol, &As[ldsrow * 64]);
      async_copy16(W + (size_t)(n0 + r) * K + k0 + scol, &Ws[ldsrow * 64]);
    }
    __syncthreads();
#pragma unroll
    for (int kk = 0; kk < 2; ++kk) {
      bf16x8 af[4], bfr[4];
#pragma unroll
      for (int f = 0; f < 4; ++f) {
        af[f]  = *(const bf16x8*)&As[(wm + f * 16 + (lane & 15)) * 64 + kk * 32 + (lane >> 4) * 8];
        bfr[f] = *(const bf16x8*)&Ws[(wn + f * 16 + (lane & 15)) * 64 + kk * 32 + (lane >> 4) * 8];
      }
#pragma unroll
      for (int fi = 0; fi < 4; ++fi)
#pragma unroll
        for (int fj = 0; fj < 4; ++fj)
          acc[fi][fj] = __builtin_amdgcn_mfma_f32_16x16x32_bf16(
              af[fi], bfr[fj], acc[fi][fj], 0, 0, 0);
    }
    __syncthreads();
  }

#pragma unroll
  for (int fj = 0; fj < 4; ++fj) {
    int col = n0 + wn + fj * 16 + (lane & 15);
    float bv = bias[col];
#pragma unroll
    for (int fi = 0; fi < 4; ++fi) {
#pragma unroll
      for (int r2 = 0; r2 < 4; ++r2) {
        int row = m0 + wm + fi * 16 + (lane >> 4) * 4 + r2;
        float v = acc[fi][fj][r2] + bv;
        if (RELU) v = fmaxf(v, 0.0f);
        if (OUTBF)
          ((unsigned short*)Cout)[(size_t)row * N + col] = f2bf(v);
        else
          ((float*)Cout)[(size_t)row * N + col] = v;
      }
    }
  }
}

// ---------------------------------------------------------------------------
// Fused GEMM (N=128) + residual add + LayerNorm -> bf16 (in-place on res ok).
// Tile 128x128, 4 waves.  Row stats: 16-lane shfl reduce + cross-wave LDS.
// ---------------------------------------------------------------------------
__global__ __launch_bounds__(256) void gemm_ln_res(
    const unsigned short* __restrict__ A, const unsigned short* __restrict__ W,
    const float* __restrict__ bias, const unsigned short* __restrict__ res,
    const float* __restrict__ gamma, const float* __restrict__ beta,
    unsigned short* __restrict__ out, int M, int K) {
  __shared__ __bf16 As[128 * 64];
  __shared__ __bf16 Ws[128 * 64];
  __shared__ float red[2][128][2];
  const int t = threadIdx.x;
  const int lane = t & 63, w = t >> 6;
  const int m0 = blockIdx.x * 128;
  const int wm = (w >> 1) * 64, wn = (w & 1) * 64;
  const int c = lane & 15, g = lane >> 4;
  f32x4 acc[4][4] = {};
  const int srow = w * 32 + (lane >> 3);
  const int scol = (lane & 7) * 8;

  for (int k0 = 0; k0 < K; k0 += 64) {
#pragma unroll
    for (int j = 0; j < 4; ++j) {
      int r = srow + j * 8;
      int ldsrow = w * 32 + j * 8;
      async_copy16(A + (size_t)(m0 + r) * K + k0 + scol, &As[ldsrow * 64]);
      async_copy16(W + (size_t)(r) * K + k0 + scol, &Ws[ldsrow * 64]);
    }
    __syncthreads();
#pragma unroll
    for (int kk = 0; kk < 2; ++kk) {
      bf16x8 af[4], bfr[4];
#pragma unroll
      for (int f = 0; f < 4; ++f) {
        af[f]  = *(const bf16x8*)&As[(wm + f * 16 + c) * 64 + kk * 32 + g * 8];
        bfr[f] = *(const bf16x8*)&Ws[(wn + f * 16 + c) * 64 + kk * 32 + g * 8];
      }
#pragma unroll
      for (int fi = 0; fi < 4; ++fi)
#pragma unroll
        for (int fj = 0; fj < 4; ++fj)
          acc[fi][fj] = __builtin_amdgcn_mfma_f32_16x16x32_bf16(
              af[fi], bfr[fj], acc[fi][fj], 0, 0, 0);
    }
    __syncthreads();
  }

  float bv[4], gl[4], bl[4];
#pragma unroll
  for (int fj = 0; fj < 4; ++fj) {
    bv[fj] = bias[wn + fj * 16 + c];
    gl[fj] = gamma[wn + fj * 16 + c];
    bl[fj] = beta[wn + fj * 16 + c];
  }
  // x = C + bias + residual
#pragma unroll
  for (int fi = 0; fi < 4; ++fi)
#pragma unroll
    for (int r2 = 0; r2 < 4; ++r2) {
      int row = wm + fi * 16 + g * 4 + r2;
      const unsigned short* rr = res + (size_t)(m0 + row) * 128;
#pragma unroll
      for (int fj = 0; fj < 4; ++fj)
        acc[fi][fj][r2] += bv[fj] + bf2f(rr[wn + fj * 16 + c]);
    }
  // row stats over this wave's 64 cols
#pragma unroll
  for (int fi = 0; fi < 4; ++fi)
#pragma unroll
    for (int r2 = 0; r2 < 4; ++r2) {
      float s_ = 0.f, q_ = 0.f;
#pragma unroll
      for (int fj = 0; fj < 4; ++fj) {
        float x = acc[fi][fj][r2];
        s_ += x; q_ += x * x;
      }
#pragma unroll
      for (int off = 1; off < 16; off <<= 1) {
        s_ += __shfl_xor(s_, off);
        q_ += __shfl_xor(q_, off);
      }
      if (c == 0) {
        int row = wm + fi * 16 + g * 4 + r2;
        red[wn >> 6][row][0] = s_;
        red[wn >> 6][row][1] = q_;
      }
    }
  __syncthreads();
#pragma unroll
  for (int fi = 0; fi < 4; ++fi)
#pragma unroll
    for (int r2 = 0; r2 < 4; ++r2) {
      int row = wm + fi * 16 + g * 4 + r2;
      float s_ = red[0][row][0] + red[1][row][0];
      float q_ = red[0][row][1] + red[1][row][1];
      float mean = s_ * 0.0078125f;
      float var = q_ * 0.0078125f - mean * mean;
      float rs = rsqrtf(var + 1e-5f);
      unsigned short* orow = out + (size_t)(m0 + row) * 128;
#pragma unroll
      for (int fj = 0; fj < 4; ++fj) {
        float y = (acc[fi][fj][r2] - mean) * rs * gl[fj] + bl[fj];
        orow[wn + fj * 16 + c] = f2bf(y);
      }
    }
}

// ---------------------------------------------------------------------------
// Fused vocab GEMM (N=256) + entropy.  Tile 128x256, 8 waves (512 thr).
// ---------------------------------------------------------------------------
__global__ __launch_bounds__(512) void gemm_entropy(
    const unsigned short* __restrict__ A, const unsigned short* __restrict__ W,
    const float* __restrict__ bias, float* __restrict__ ent, int K) {
  __shared__ __bf16 As[128 * 64];
  __shared__ __bf16 Ws[256 * 64];
  __shared__ float redm[4][128], redz[4][128], redx[4][128];
  const int t = threadIdx.x;
  const int lane = t & 63, w = t >> 6;
  const int m0 = blockIdx.x * 128;
  const int wm = (w >> 2) * 64, wn = (w & 3) * 64;
  const int c = lane & 15, g = lane >> 4;
  f32x4 acc[4][4] = {};
  const int srow = w * 8 + (lane >> 3);
  const int scol = (lane & 7) * 8;

  for (int k0 = 0; k0 < K; k0 += 64) {
#pragma unroll
    for (int j = 0; j < 2; ++j)
      async_copy16(A + (size_t)(m0 + srow + j * 64) * K + k0 + scol,
                   &As[(w * 8 + j * 64) * 64]);
#pragma unroll
    for (int j = 0; j < 4; ++j)
      async_copy16(W + (size_t)(srow + j * 64) * K + k0 + scol,
                   &Ws[(w * 8 + j * 64) * 64]);
    __syncthreads();
#pragma unroll
    for (int kk = 0; kk < 2; ++kk) {
      bf16x8 af[4], bfr[4];
#pragma unroll
      for (int f = 0; f < 4; ++f) {
        af[f]  = *(const bf16x8*)&As[(wm + f * 16 + c) * 64 + kk * 32 + g * 8];
        bfr[f] = *(const bf16x8*)&Ws[(wn + f * 16 + c) * 64 + kk * 32 + g * 8];
      }
#pragma unroll
      for (int fi = 0; fi < 4; ++fi)
#pragma unroll
        for (int fj = 0; fj < 4; ++fj)
          acc[fi][fj] = __builtin_amdgcn_mfma_f32_16x16x32_bf16(
              af[fi], bfr[fj], acc[fi][fj], 0, 0, 0);
    }
    __syncthreads();
  }

  float bv[4];
#pragma unroll
  for (int fj = 0; fj < 4; ++fj) bv[fj] = bias[wn + fj * 16 + c];
#pragma unroll
  for (int fi = 0; fi < 4; ++fi)
#pragma unroll
    for (int fj = 0; fj < 4; ++fj)
#pragma unroll
      for (int r2 = 0; r2 < 4; ++r2) acc[fi][fj][r2] += bv[fj];

  // phase 1: row max
#pragma unroll
  for (int fi = 0; fi < 4; ++fi)
#pragma unroll
    for (int r2 = 0; r2 < 4; ++r2) {
      float m_ = -1e30f;
#pragma unroll
      for (int fj = 0; fj < 4; ++fj) m_ = fmaxf(m_, acc[fi][fj][r2]);
#pragma unroll
      for (int off = 1; off < 16; off <<= 1) m_ = fmaxf(m_, __shfl_xor(m_, off));
      if (c == 0) redm[wn >> 6][wm + fi * 16 + g * 4 + r2] = m_;
    }
  __syncthreads();
  // phase 2: exp sums
  float mr[4][4];
#pragma unroll
  for (int fi = 0; fi < 4; ++fi)
#pragma unroll
    for (int r2 = 0; r2 < 4; ++r2) {
      int row = wm + fi * 16 + g * 4 + r2;
      float m4 = fmaxf(fmaxf(redm[0][row], redm[1][row]),
                       fmaxf(redm[2][row], redm[3][row]));
      mr[fi][r2] = m4;
      float z_ = 0.f, sx_ = 0.f;
#pragma unroll
      for (int fj = 0; fj < 4; ++fj) {
        float x = acc[fi][fj][r2];
        float e = __expf(x - m4);
        z_ += e; sx_ += e * x;
      }
#pragma unroll
      for (int off = 1; off < 16; off <<= 1) {
        z_ += __shfl_xor(z_, off);
        sx_ += __shfl_xor(sx_, off);
      }
      if (c == 0) {
        redz[wn >> 6][row] = z_;
        redx[wn >> 6][row] = sx_;
      }
    }
  __syncthreads();
  if ((w & 3) == 0 && c == 0) {
#pragma unroll
    for (int fi = 0; fi < 4; ++fi)
#pragma unroll
      for (int r2 = 0; r2 < 4; ++r2) {
        int row = wm + fi * 16 + g * 4 + r2;
        float Z = (redz[0][row] + redz[1][row]) + (redz[2][row] + redz[3][row]);
        float SX = (redx[0][row] + redx[1][row]) + (redx[2][row] + redx[3][row]);
        ent[m0 + row] = mr[fi][r2] + logf(Z) - SX / Z;
      }
  }
}

// ---------------------------------------------------------------------------
// MFMA flash attention, register-resident P.  Q pre-scaled by scale*log2e.
// One block (512 thr = 8 waves) per (batch, head).
// ---------------------------------------------------------------------------
__global__ __launch_bounds__(512, 4) void attn_mfma(
    const unsigned short* __restrict__ qkv, unsigned short* __restrict__ obf) {
  __shared__ __bf16 Ks[512 * 40];
  __shared__ __bf16 Vt[32 * 520];

  const int hh = blockIdx.x & 3, bl = blockIdx.x >> 2;
  const int t = threadIdx.x;
  const int lane = t & 63, wv = t >> 6;
  const int c = lane & 15, g = lane >> 4;
  const size_t tok0 = (size_t)bl * 512;

  {
    const unsigned short* kr = qkv + (tok0 + t) * 384 + 128 + hh * 32;
    bf16x8 k0 = *(const bf16x8*)(kr);
    bf16x8 k1 = *(const bf16x8*)(kr + 8);
    bf16x8 k2 = *(const bf16x8*)(kr + 16);
    bf16x8 k3 = *(const bf16x8*)(kr + 24);
    __bf16* kd = Ks + t * 40;
    *(bf16x8*)(kd + 0) = k0;  *(bf16x8*)(kd + 8) = k1;
    *(bf16x8*)(kd + 16) = k2; *(bf16x8*)(kd + 24) = k3;
    const unsigned short* vr = kr + 128;
    bf16x8 v0 = *(const bf16x8*)(vr);
    bf16x8 v1 = *(const bf16x8*)(vr + 8);
    bf16x8 v2 = *(const bf16x8*)(vr + 16);
    bf16x8 v3 = *(const bf16x8*)(vr + 24);
#pragma unroll
    for (int i = 0; i < 8; ++i) {
      Vt[(i)      * 520 + t] = v0[i];
      Vt[(i + 8)  * 520 + t] = v1[i];
      Vt[(i + 16) * 520 + t] = v2[i];
      Vt[(i + 24) * 520 + t] = v3[i];
    }
  }

  bf16x8 qb[4];
  {
    const unsigned short* qp = qkv + (tok0 + wv * 64) * 384 + hh * 32;
#pragma unroll
    for (int qf = 0; qf < 4; ++qf)
      qb[qf] = *(const bf16x8*)(qp + (size_t)(qf * 16 + c) * 384 + g * 8);
  }
  __syncthreads();

  f32x4 ot[4][2] = {};
  float l[4] = {0.f, 0.f, 0.f, 0.f};
  const f32x4 zz = {0.f, 0.f, 0.f, 0.f};

  for (int kt = 0; kt < 8; ++kt) {
    bf16x8 ka[4];
#pragma unroll
    for (int kf = 0; kf < 4; ++kf)
      ka[kf] = *(const bf16x8*)&Ks[(kt * 64 + kf * 16 + c) * 40 + g * 8];
    bf16x8 vb[2][2];
#pragma unroll
    for (int hf = 0; hf < 2; ++hf)
#pragma unroll
      for (int ksl = 0; ksl < 2; ++ksl)
        vb[hf][ksl] =
            *(const bf16x8*)&Vt[(hf * 16 + c) * 520 + kt * 64 + ksl * 32 + g * 8];

#pragma unroll
    for (int qf = 0; qf < 4; ++qf) {
      f32x4 sA = __builtin_amdgcn_mfma_f32_16x16x32_bf16(ka[0], qb[qf], zz, 0, 0, 0);
      f32x4 sB = __builtin_amdgcn_mfma_f32_16x16x32_bf16(ka[1], qb[qf], zz, 0, 0, 0);
      f32x4 sC = __builtin_amdgcn_mfma_f32_16x16x32_bf16(ka[2], qb[qf], zz, 0, 0, 0);
      f32x4 sD = __builtin_amdgcn_mfma_f32_16x16x32_bf16(ka[3], qb[qf], zz, 0, 0, 0);

      {
        float pa0 = EXP2(sA[0]), pa1 = EXP2(sA[1]);
        float pa2 = EXP2(sA[2]), pa3 = EXP2(sA[3]);
        float pb0 = EXP2(sB[0]), pb1 = EXP2(sB[1]);
        float pb2 = EXP2(sB[2]), pb3 = EXP2(sB[3]);
        l[qf] += ((pa0 + pa1) + (pa2 + pa3)) + ((pb0 + pb1) + (pb2 + pb3));
        unsigned int w00 = cvtpk_bf16(pa0, pa1), w01 = cvtpk_bf16(pa2, pa3);
        unsigned int w10 = cvtpk_bf16(pb0, pb1), w11 = cvtpk_bf16(pb2, pb3);
        plswap32(w00, w10); plswap16(w00, w10);
        plswap32(w01, w11); plswap16(w01, w11);
        union { unsigned int u[4]; bf16x8 v; } pk;
        pk.u[0] = w00; pk.u[1] = w01; pk.u[2] = w10; pk.u[3] = w11;
        ot[qf][0] = __builtin_amdgcn_mfma_f32_16x16x32_bf16(vb[0][0], pk.v,
                                                            ot[qf][0], 0, 0, 0);
        ot[qf][1] = __builtin_amdgcn_mfma_f32_16x16x32_bf16(vb[1][0], pk.v,
                                                            ot[qf][1], 0, 0, 0);
      }
      {
        float pa0 = EXP2(sC[0]), pa1 = EXP2(sC[1]);
        float pa2 = EXP2(sC[2]), pa3 = EXP2(sC[3]);
        float pb0 = EXP2(sD[0]), pb1 = EXP2(sD[1]);
        float pb2 = EXP2(sD[2]), pb3 = EXP2(sD[3]);
        l[qf] += ((pa0 + pa1) + (pa2 + pa3)) + ((pb0 + pb1) + (pb2 + pb3));
        unsigned int w00 = cvtpk_bf16(pa0, pa1), w01 = cvtpk_bf16(pa2, pa3);
        unsigned int w10 = cvtpk_bf16(pb0, pb1), w11 = cvtpk_bf16(pb2, pb3);
        plswap32(w00, w10); plswap16(w00, w10);
        plswap32(w01, w11); plswap16(w01, w11);
        union { unsigned int u[4]; bf16x8 v; } pk;
        pk.u[0] = w00; pk.u[1] = w01; pk.u[2] = w10; pk.u[3] = w11;
        ot[qf][0] = __builtin_amdgcn_mfma_f32_16x16x32_bf16(vb[0][1], pk.v,
                                                            ot[qf][0], 0, 0, 0);
        ot[qf][1] = __builtin_amdgcn_mfma_f32_16x16x32_bf16(vb[1][1], pk.v,
                                                            ot[qf][1], 0, 0, 0);
      }
    }
  }

#pragma unroll
  for (int qf = 0; qf < 4; ++qf) {
    l[qf] += __shfl_xor(l[qf], 16);
    l[qf] += __shfl_xor(l[qf], 32);
  }
#pragma unroll
  for (int qf = 0; qf < 4; ++qf) {
    float rl = 1.0f / l[qf];
#pragma unroll
    for (int hf = 0; hf < 2; ++hf) {
      ushort4 pk;
      pk.x = f2bf(ot[qf][hf][0] * rl);
      pk.y = f2bf(ot[qf][hf][1] * rl);
      pk.z = f2bf(ot[qf][hf][2] * rl);
      pk.w = f2bf(ot[qf][hf][3] * rl);
      *(ushort4*)(obf + (tok0 + wv * 64 + qf * 16 + c) * 128 + hh * 32 +
                  hf * 16 + g * 4) = pk;
    }
  }
}

// ---------------------------------------------------------------------------
__global__ __launch_bounds__(64) void avg_entropy_kernel(
    const float* __restrict__ ent, float* __restrict__ out) {
  int s = blockIdx.x, lane = threadIdx.x;
  float a = 0.f;
  for (int b = lane; b < 256; b += 64) a += ent[(size_t)b * 512 + s];
#pragma unroll
  for (int off = 32; off; off >>= 1) a += __shfl_xor(a, off);
  if (lane == 0) out[s] = a * 0.00390625f;
}

__global__ __launch_bounds__(512) void seg_kernel(float* out) {
  __shared__ int cs[512];
  int i = threadIdx.x;
  float e = out[i];
  cs[i] = (i >= 1 && e > 4.0f) ? 1 : 0;
  __syncthreads();
  for (int off = 1; off < 512; off <<= 1) {
    int v = (i >= off) ? cs[i - off] : 0;
    __syncthreads();
    cs[i] += v;
    __syncthreads();
  }
  out[512 + i] = (float)cs[i];
}

// ---------------------------------------------------------------------------
extern "C" void kernel_launch(void* const* d_in, const int* in_sizes, int n_in,
                              void* d_out, int out_size, void* d_ws,
                              size_t ws_size, hipStream_t stream) {
  (void)in_sizes; (void)n_in; (void)out_size; (void)ws_size;
  const int*   input_bytes = (const int*)d_in[0];
  const float* emb    = (const float*)d_in[1];
  const float* pos    = (const float*)d_in[2];
  const float* ln_g   = (const float*)d_in[3];
  const float* ln_b   = (const float*)d_in[4];
  const float* attn_w = (const float*)d_in[5];
  const float* attn_b = (const float*)d_in[6];
  const float* out_w  = (const float*)d_in[7];
  const float* out_b  = (const float*)d_in[8];
  const float* ff1_w  = (const float*)d_in[9];
  const float* ff1_b  = (const float*)d_in[10];
  const float* ff2_w  = (const float*)d_in[11];
  const float* ff2_b  = (const float*)d_in[12];
  const float* n1_g   = (const float*)d_in[13];
  const float* n1_b   = (const float*)d_in[14];
  const float* n2_g   = (const float*)d_in[15];
  const float* n2_b   = (const float*)d_in[16];
  const float* proj_w = (const float*)d_in[17];
  const float* proj_b = (const float*)d_in[18];

  char* ws = (char*)d_ws;
  unsigned short* hbf  = (unsigned short*)(ws);                // 32 MB
  unsigned short* qkvc = (unsigned short*)(ws + 33554432);     // 50.3 MB
  unsigned short* obf  = (unsigned short*)(ws + 83886080);     // 32 MB
  unsigned short* ff1t = (unsigned short*)(ws + 117440512);    // 32 MB
  unsigned short* wbf  = (unsigned short*)(ws + 150994944);    // ~0.85 MB
  float*          absb = (float*)(ws + 152043520);             // 3 KB
  float*          entb = (float*)(ws + 152174592);             // 0.5 MB

  unsigned short* attnw_bf = wbf;
  unsigned short* outw_bf  = wbf + 98304;
  unsigned short* ff1_bf   = wbf + 131072;
  unsigned short* ff2_bf   = wbf + 262144;
  unsigned short* projw_bf = wbf + 393216;

  conv_attn_w<<<384, 256, 0, stream>>>(attn_w, attnw_bf);
  conv_attn_b<<<3, 256, 0, stream>>>(attn_b, absb);
  f32_to_bf16<<<128, 256, 0, stream>>>(out_w, outw_bf, 32768);
  f32_to_bf16<<<512, 256, 0, stream>>>(ff1_w, ff1_bf, 131072);
  f32_to_bf16<<<512, 256, 0, stream>>>(ff2_w, ff2_bf, 131072);
  f32_to_bf16<<<128, 256, 0, stream>>>(proj_w, projw_bf, 32768);

  embed_ln<<<32768, 256, 0, stream>>>(input_bytes, emb, pos, ln_g, ln_b, hbf);

  for (int l = 0; l < 2; ++l) {
    for (int ch = 0; ch < 2; ++ch) {
      gemm_bf16<0, 1><<<dim3(3, 512), 256, 0, stream>>>(
          hbf + (size_t)ch * 65536 * 128, attnw_bf + l * 49152,
          absb + l * 384, qkvc, 65536, 384, 128);
      attn_mfma<<<512, 512, 0, stream>>>(qkvc,
                                         obf + (size_t)ch * 65536 * 128);
    }
    // fused out-proj + residual + LN1 (in place on hbf)
    gemm_ln_res<<<1024, 256, 0, stream>>>(
        obf, outw_bf + l * 16384, out_b + l * 128, hbf,
        n1_g + l * 128, n1_b + l * 128, hbf, 131072, 128);
    // FFN: ff1 (relu, bf16) then fused ff2 + residual + LN2, 4 chunks
    for (int tc = 0; tc < 4; ++tc) {
      gemm_bf16<1, 1><<<dim3(4, 256), 256, 0, stream>>>(
          hbf + (size_t)tc * 32768 * 128, ff1_bf + l * 65536,
          ff1_b + l * 512, ff1t, 32768, 512, 128);
      gemm_ln_res<<<256, 256, 0, stream>>>(
          ff1t, ff2_bf + l * 65536, ff2_b + l * 128,
          hbf + (size_t)tc * 32768 * 128, n2_g + l * 128, n2_b + l * 128,
          hbf + (size_t)tc * 32768 * 128, 32768, 512);
    }
  }

  // fused vocab projection + entropy
  gemm_entropy<<<1024, 512, 0, stream>>>(hbf, projw_bf, proj_b, entb, 128);
  avg_entropy_kernel<<<512, 64, 0, stream>>>(entb, (float*)d_out);
  seg_kernel<<<1, 512, 0, stream>>>((float*)d_out);
}

// Round 5
// 550.488 us; speedup vs baseline: 1.6464x; 1.2596x over previous
//
#include <hip/hip_runtime.h>

// ---------------------------------------------------------------------------
// EntropyCalculator: 2-layer post-norm transformer encoder + entropy head.
// B=256 S=512 D=128 H=4 HD=32 FF=512 V=256
// bf16 residual stream; fused FFN; fused GEMM+LN and GEMM+entropy epilogues.
// ---------------------------------------------------------------------------

#define AS1 __attribute__((address_space(1)))
#define AS3 __attribute__((address_space(3)))

typedef __bf16 bf16x8 __attribute__((ext_vector_type(8)));
typedef __bf16 bf16x4 __attribute__((ext_vector_type(4)));
typedef float  f32x4  __attribute__((ext_vector_type(4)));

__device__ __forceinline__ unsigned short f2bf(float f) {
  union { float f; unsigned int u; } c; c.f = f;
  unsigned int u = c.u;
  u += 0x7FFFu + ((u >> 16) & 1u);   // round-to-nearest-even
  return (unsigned short)(u >> 16);
}
__device__ __forceinline__ float bf2f(unsigned short u) {
  union { unsigned int u; float f; } c; c.u = ((unsigned int)u) << 16;
  return c.f;
}

__device__ __forceinline__ float EXP2(float x) {
#if __has_builtin(__builtin_amdgcn_exp2f)
  return __builtin_amdgcn_exp2f(x);
#else
  return exp2f(x);
#endif
}

__device__ __forceinline__ void async_copy16(const void* g, void* l) {
  __builtin_amdgcn_global_load_lds((AS1 void*)(void*)g, (AS3 void*)l, 16, 0, 0);
}

__device__ __forceinline__ unsigned int cvtpk_bf16(float lo, float hi) {
  unsigned int r;
  asm("v_cvt_pk_bf16_f32 %0, %1, %2" : "=v"(r) : "v"(lo), "v"(hi));
  return r;
}
__device__ __forceinline__ void plswap32(unsigned int& a, unsigned int& b) {
  asm("v_permlane32_swap_b32 %0, %1" : "+v"(a), "+v"(b));
}
__device__ __forceinline__ void plswap16(unsigned int& a, unsigned int& b) {
  asm("v_permlane16_swap_b32 %0, %1" : "+v"(a), "+v"(b));
}

// ---------------------------------------------------------------------------
// weight conversions
// ---------------------------------------------------------------------------
__global__ void f32_to_bf16(const float* __restrict__ src,
                            unsigned short* __restrict__ dst, int n) {
  int i = blockIdx.x * blockDim.x + threadIdx.x;
  if (i < n) dst[i] = f2bf(src[i]);
}

// Permute a [N][K] weight into MFMA-B-fragment lane order:
// dst[(row>>4)*(16K) + (k>>5)*512 + (row&15)*32 + (k&31)] so a wave's
// 16x32 fragment tile is one contiguous 1KB block, lane-ordered.
__global__ void conv_perm(const float* __restrict__ src,
                          unsigned short* __restrict__ dst, int K, int n) {
  int i = blockIdx.x * 256 + threadIdx.x;
  if (i >= n) return;
  int l = i >> 16, rem = i & 65535;            // perLayer = 65536
  int row = rem / K, k = rem - row * K;
  int d = (row >> 4) * (K * 16) + (k >> 5) * 512 + (row & 15) * 32 + (k & 31);
  dst[(l << 16) + d] = f2bf(src[i]);
}

// attn_w with Q rows pre-scaled by (1/sqrt(HD))*log2(e)
#define QSCALE 0.2550602989892646f
__global__ void conv_attn_w(const float* __restrict__ src,
                            unsigned short* __restrict__ dst) {
  int i = blockIdx.x * 256 + threadIdx.x;  // 98304
  int r = (i >> 7) % 384;
  float v = src[i];
  if (r < 128) v *= QSCALE;
  dst[i] = f2bf(v);
}
__global__ void conv_attn_b(const float* __restrict__ src,
                            float* __restrict__ dst) {
  int i = blockIdx.x * 256 + threadIdx.x;  // 768
  if (i < 768) {
    float v = src[i];
    if ((i % 384) < 128) v *= QSCALE;
    dst[i] = v;
  }
}

// ---------------------------------------------------------------------------
// Embedding + LayerNorm -> bf16 residual stream.  One wave per token.
// ---------------------------------------------------------------------------
__global__ __launch_bounds__(256) void embed_ln(
    const int* __restrict__ bytes, const float* __restrict__ emb,
    const float* __restrict__ pos, const float* __restrict__ g,
    const float* __restrict__ bta, unsigned short* __restrict__ hbf) {
  int wv = threadIdx.x >> 6, lane = threadIdx.x & 63;
  int tok = blockIdx.x * 4 + wv;
  int s = tok & 511;
  int bidx = bytes[tok];
  const float* e = emb + (size_t)bidx * 128;
  const float* p = pos + (size_t)s * 128;
  float x0 = e[lane] + p[lane];
  float x1 = e[lane + 64] + p[lane + 64];
  float sum = x0 + x1, ssq = x0 * x0 + x1 * x1;
#pragma unroll
  for (int off = 32; off; off >>= 1) {
    sum += __shfl_xor(sum, off);
    ssq += __shfl_xor(ssq, off);
  }
  float mean = sum * 0.0078125f;
  float var = ssq * 0.0078125f - mean * mean;
  float rs = rsqrtf(var + 1e-5f);
  float y0 = (x0 - mean) * rs * g[lane] + bta[lane];
  float y1 = (x1 - mean) * rs * g[lane + 64] + bta[lane + 64];
  size_t o = (size_t)tok * 128;
  hbf[o + lane] = f2bf(y0); hbf[o + lane + 64] = f2bf(y1);
}

// ---------------------------------------------------------------------------
// bf16 MFMA GEMM:  C[M,N] = A[M,K] @ W[N,K]^T + bias  (bf16 out option)
// 128x128 tile, BK=64, 4 waves.
// ---------------------------------------------------------------------------
template <int RELU, int OUTBF>
__global__ __launch_bounds__(256) void gemm_bf16(
    const unsigned short* __restrict__ A, const unsigned short* __restrict__ W,
    const float* __restrict__ bias, void* __restrict__ Cout,
    int M, int N, int K) {
  __shared__ __bf16 As[128 * 64];
  __shared__ __bf16 Ws[128 * 64];
  const int t = threadIdx.x;
  const int lane = t & 63, w = t >> 6;
  const int m0 = blockIdx.y * 128, n0 = blockIdx.x * 128;
  const int wm = (w >> 1) * 64, wn = (w & 1) * 64;
  f32x4 acc[4][4] = {};
  const int srow = w * 32 + (lane >> 3);
  const int scol = (lane & 7) * 8;

  for (int k0 = 0; k0 < K; k0 += 64) {
#pragma unroll
    for (int j = 0; j < 4; ++j) {
      int r = srow + j * 8;
      int ldsrow = w * 32 + j * 8;
      async_copy16(A + (size_t)(m0 + r) * K + k0 + scol, &As[ldsrow * 64]);
      async_copy16(W + (size_t)(n0 + r) * K + k0 + scol, &Ws[ldsrow * 64]);
    }
    __syncthreads();
#pragma unroll
    for (int kk = 0; kk < 2; ++kk) {
      bf16x8 af[4], bfr[4];
#pragma unroll
      for (int f = 0; f < 4; ++f) {
        af[f]  = *(const bf16x8*)&As[(wm + f * 16 + (lane & 15)) * 64 + kk * 32 + (lane >> 4) * 8];
        bfr[f] = *(const bf16x8*)&Ws[(wn + f * 16 + (lane & 15)) * 64 + kk * 32 + (lane >> 4) * 8];
      }
#pragma unroll
      for (int fi = 0; fi < 4; ++fi)
#pragma unroll
        for (int fj = 0; fj < 4; ++fj)
          acc[fi][fj] = __builtin_amdgcn_mfma_f32_16x16x32_bf16(
              af[fi], bfr[fj], acc[fi][fj], 0, 0, 0);
    }
    __syncthreads();
  }

#pragma unroll
  for (int fj = 0; fj < 4; ++fj) {
    int col = n0 + wn + fj * 16 + (lane & 15);
    float bv = bias[col];
#pragma unroll
    for (int fi = 0; fi < 4; ++fi) {
#pragma unroll
      for (int r2 = 0; r2 < 4; ++r2) {
        int row = m0 + wm + fi * 16 + (lane >> 4) * 4 + r2;
        float v = acc[fi][fj][r2] + bv;
        if (RELU) v = fmaxf(v, 0.0f);
        if (OUTBF)
          ((unsigned short*)Cout)[(size_t)row * N + col] = f2bf(v);
        else
          ((float*)Cout)[(size_t)row * N + col] = v;
      }
    }
  }
}

// ---------------------------------------------------------------------------
// Fused GEMM (N=128) + residual add + LayerNorm -> bf16 (in-place on res ok).
// ---------------------------------------------------------------------------
__global__ __launch_bounds__(256) void gemm_ln_res(
    const unsigned short* __restrict__ A, const unsigned short* __restrict__ W,
    const float* __restrict__ bias, const unsigned short* __restrict__ res,
    const float* __restrict__ gamma, const float* __restrict__ beta,
    unsigned short* __restrict__ out, int M, int K) {
  __shared__ __bf16 As[128 * 64];
  __shared__ __bf16 Ws[128 * 64];
  __shared__ float red[2][128][2];
  const int t = threadIdx.x;
  const int lane = t & 63, w = t >> 6;
  const int m0 = blockIdx.x * 128;
  const int wm = (w >> 1) * 64, wn = (w & 1) * 64;
  const int c = lane & 15, g = lane >> 4;
  f32x4 acc[4][4] = {};
  const int srow = w * 32 + (lane >> 3);
  const int scol = (lane & 7) * 8;

  for (int k0 = 0; k0 < K; k0 += 64) {
#pragma unroll
    for (int j = 0; j < 4; ++j) {
      int r = srow + j * 8;
      int ldsrow = w * 32 + j * 8;
      async_copy16(A + (size_t)(m0 + r) * K + k0 + scol, &As[ldsrow * 64]);
      async_copy16(W + (size_t)(r) * K + k0 + scol, &Ws[ldsrow * 64]);
    }
    __syncthreads();
#pragma unroll
    for (int kk = 0; kk < 2; ++kk) {
      bf16x8 af[4], bfr[4];
#pragma unroll
      for (int f = 0; f < 4; ++f) {
        af[f]  = *(const bf16x8*)&As[(wm + f * 16 + c) * 64 + kk * 32 + g * 8];
        bfr[f] = *(const bf16x8*)&Ws[(wn + f * 16 + c) * 64 + kk * 32 + g * 8];
      }
#pragma unroll
      for (int fi = 0; fi < 4; ++fi)
#pragma unroll
        for (int fj = 0; fj < 4; ++fj)
          acc[fi][fj] = __builtin_amdgcn_mfma_f32_16x16x32_bf16(
              af[fi], bfr[fj], acc[fi][fj], 0, 0, 0);
    }
    __syncthreads();
  }

  float bv[4], gl[4], bl[4];
#pragma unroll
  for (int fj = 0; fj < 4; ++fj) {
    bv[fj] = bias[wn + fj * 16 + c];
    gl[fj] = gamma[wn + fj * 16 + c];
    bl[fj] = beta[wn + fj * 16 + c];
  }
#pragma unroll
  for (int fi = 0; fi < 4; ++fi)
#pragma unroll
    for (int r2 = 0; r2 < 4; ++r2) {
      int row = wm + fi * 16 + g * 4 + r2;
      const unsigned short* rr = res + (size_t)(m0 + row) * 128;
#pragma unroll
      for (int fj = 0; fj < 4; ++fj)
        acc[fi][fj][r2] += bv[fj] + bf2f(rr[wn + fj * 16 + c]);
    }
#pragma unroll
  for (int fi = 0; fi < 4; ++fi)
#pragma unroll
    for (int r2 = 0; r2 < 4; ++r2) {
      float s_ = 0.f, q_ = 0.f;
#pragma unroll
      for (int fj = 0; fj < 4; ++fj) {
        float x = acc[fi][fj][r2];
        s_ += x; q_ += x * x;
      }
#pragma unroll
      for (int off = 1; off < 16; off <<= 1) {
        s_ += __shfl_xor(s_, off);
        q_ += __shfl_xor(q_, off);
      }
      if (c == 0) {
        int row = wm + fi * 16 + g * 4 + r2;
        red[wn >> 6][row][0] = s_;
        red[wn >> 6][row][1] = q_;
      }
    }
  __syncthreads();
#pragma unroll
  for (int fi = 0; fi < 4; ++fi)
#pragma unroll
    for (int r2 = 0; r2 < 4; ++r2) {
      int row = wm + fi * 16 + g * 4 + r2;
      float s_ = red[0][row][0] + red[1][row][0];
      float q_ = red[0][row][1] + red[1][row][1];
      float mean = s_ * 0.0078125f;
      float var = q_ * 0.0078125f - mean * mean;
      float rs = rsqrtf(var + 1e-5f);
      unsigned short* orow = out + (size_t)(m0 + row) * 128;
#pragma unroll
      for (int fj = 0; fj < 4; ++fj) {
        float y = (acc[fi][fj][r2] - mean) * rs * gl[fj] + bl[fj];
        orow[wn + fj * 16 + c] = f2bf(y);
      }
    }
}

// ---------------------------------------------------------------------------
// Fused FFN: out = LN(res + b2 + relu(res @ W1^T + b1) @ W2^T).
// One block = 128 tokens, 512 thr (8 waves as 2x4).  A and G tiles in LDS;
// W1/W2 read directly from L2 in pre-permuted fragment order (conv_perm).
// ---------------------------------------------------------------------------
__global__ __launch_bounds__(512, 4) void ffn_fused(
    const unsigned short* __restrict__ hin,
    const unsigned short* __restrict__ W1p, const float* __restrict__ b1,
    const unsigned short* __restrict__ W2p, const float* __restrict__ b2,
    const float* __restrict__ gamma, const float* __restrict__ beta,
    unsigned short* __restrict__ out) {
  __shared__ __bf16 As[128 * 128];
  __shared__ __bf16 Gs[128 * 128];
  __shared__ float red[4][128][2];
  const int t = threadIdx.x;
  const int lane = t & 63, w = t >> 6;
  const int c = lane & 15, g = lane >> 4;
  const int wm = (w >> 2) * 64;        // token-row group
  const int wn = (w & 3) * 32;         // col group
  const size_t m0 = (size_t)blockIdx.x * 128;
  const int lidx = (c * 4 + g) * 8;    // lane offset into permuted W frag

  // stage A tile (linear, coalesced): 2048 granules of 16B
  {
    const unsigned short* Ab = hin + m0 * 128;
#pragma unroll
    for (int j = 0; j < 4; ++j) {
      int gi = j * 512 + t;
      char* ldsbase = (char*)As + (j * 512 + w * 64) * 16;
      async_copy16(Ab + (size_t)gi * 8, ldsbase);
    }
  }
  __syncthreads();

  f32x4 acc2[4][2] = {};
  for (int f = 0; f < 4; ++f) {
    // ---- gemm1 chunk: G_f = relu(A @ W1_f^T + b1_f) ----
    f32x4 acc1[4][2] = {};
    const unsigned short* w1b = W1p + (f * 8 + (w & 3) * 2) * 2048;
#pragma unroll
    for (int kk = 0; kk < 4; ++kk) {
      bf16x8 af[4];
#pragma unroll
      for (int fi = 0; fi < 4; ++fi)
        af[fi] = *(const bf16x8*)&As[(wm + fi * 16 + c) * 128 + kk * 32 + g * 8];
#pragma unroll
      for (int fj = 0; fj < 2; ++fj) {
        bf16x8 bw = *(const bf16x8*)(w1b + fj * 2048 + kk * 512 + lidx);
#pragma unroll
        for (int fi = 0; fi < 4; ++fi)
          acc1[fi][fj] = __builtin_amdgcn_mfma_f32_16x16x32_bf16(
              af[fi], bw, acc1[fi][fj], 0, 0, 0);
      }
    }
    float bv1[2] = {b1[f * 128 + wn + c], b1[f * 128 + wn + 16 + c]};
#pragma unroll
    for (int fi = 0; fi < 4; ++fi)
#pragma unroll
      for (int fj = 0; fj < 2; ++fj)
#pragma unroll
        for (int r = 0; r < 4; ++r) {
          int row = wm + fi * 16 + g * 4 + r;
          float v = fmaxf(acc1[fi][fj][r] + bv1[fj], 0.0f);
          *(unsigned short*)&Gs[row * 128 + wn + fj * 16 + c] = f2bf(v);
        }
    __syncthreads();
    // ---- gemm2 partial: acc2 += G_f @ W2_f^T ----
    const unsigned short* w2b = W2p + ((w & 3) * 2) * 8192 + f * 2048;
#pragma unroll
    for (int kk = 0; kk < 4; ++kk) {
      bf16x8 gf[4];
#pragma unroll
      for (int fi = 0; fi < 4; ++fi)
        gf[fi] = *(const bf16x8*)&Gs[(wm + fi * 16 + c) * 128 + kk * 32 + g * 8];
#pragma unroll
      for (int fj = 0; fj < 2; ++fj) {
        bf16x8 bw = *(const bf16x8*)(w2b + fj * 8192 + kk * 512 + lidx);
#pragma unroll
        for (int fi = 0; fi < 4; ++fi)
          acc2[fi][fj] = __builtin_amdgcn_mfma_f32_16x16x32_bf16(
              gf[fi], bw, acc2[fi][fj], 0, 0, 0);
      }
    }
    __syncthreads();
  }

  // ---- epilogue: bias + residual + LayerNorm ----
  float bv2[2] = {b2[wn + c], b2[wn + 16 + c]};
  float xv[4][2][4];
#pragma unroll
  for (int fi = 0; fi < 4; ++fi)
#pragma unroll
    for (int r = 0; r < 4; ++r) {
      int row = wm + fi * 16 + g * 4 + r;
#pragma unroll
      for (int fj = 0; fj < 2; ++fj) {
        float res = bf2f(*(const unsigned short*)&As[row * 128 + wn + fj * 16 + c]);
        xv[fi][fj][r] = acc2[fi][fj][r] + bv2[fj] + res;
      }
    }
#pragma unroll
  for (int fi = 0; fi < 4; ++fi)
#pragma unroll
    for (int r = 0; r < 4; ++r) {
      float a0 = xv[fi][0][r], a1 = xv[fi][1][r];
      float s_ = a0 + a1, q_ = a0 * a0 + a1 * a1;
#pragma unroll
      for (int off = 1; off < 16; off <<= 1) {
        s_ += __shfl_xor(s_, off);
        q_ += __shfl_xor(q_, off);
      }
      if (c == 0) {
        int row = wm + fi * 16 + g * 4 + r;
        red[w & 3][row][0] = s_;
        red[w & 3][row][1] = q_;
      }
    }
  __syncthreads();
  float gl[2] = {gamma[wn + c], gamma[wn + 16 + c]};
  float bl[2] = {beta[wn + c], beta[wn + 16 + c]};
#pragma unroll
  for (int fi = 0; fi < 4; ++fi)
#pragma unroll
    for (int r = 0; r < 4; ++r) {
      int row = wm + fi * 16 + g * 4 + r;
      float s_ = (red[0][row][0] + red[1][row][0]) + (red[2][row][0] + red[3][row][0]);
      float q_ = (red[0][row][1] + red[1][row][1]) + (red[2][row][1] + red[3][row][1]);
      float mean = s_ * 0.0078125f;
      float var = q_ * 0.0078125f - mean * mean;
      float rs = rsqrtf(var + 1e-5f);
#pragma unroll
      for (int fj = 0; fj < 2; ++fj) {
        float y = (xv[fi][fj][r] - mean) * rs * gl[fj] + bl[fj];
        out[(m0 + row) * 128 + wn + fj * 16 + c] = f2bf(y);
      }
    }
}

// ---------------------------------------------------------------------------
// Fused vocab GEMM (N=256) + entropy.  Tile 128x256, 8 waves (512 thr).
// ---------------------------------------------------------------------------
__global__ __launch_bounds__(512) void gemm_entropy(
    const unsigned short* __restrict__ A, const unsigned short* __restrict__ W,
    const float* __restrict__ bias, float* __restrict__ ent, int K) {
  __shared__ __bf16 As[128 * 64];
  __shared__ __bf16 Ws[256 * 64];
  __shared__ float redm[4][128], redz[4][128], redx[4][128];
  const int t = threadIdx.x;
  const int lane = t & 63, w = t >> 6;
  const int m0 = blockIdx.x * 128;
  const int wm = (w >> 2) * 64, wn = (w & 3) * 64;
  const int c = lane & 15, g = lane >> 4;
  f32x4 acc[4][4] = {};
  const int srow = w * 8 + (lane >> 3);
  const int scol = (lane & 7) * 8;

  for (int k0 = 0; k0 < K; k0 += 64) {
#pragma unroll
    for (int j = 0; j < 2; ++j)
      async_copy16(A + (size_t)(m0 + srow + j * 64) * K + k0 + scol,
                   &As[(w * 8 + j * 64) * 64]);
#pragma unroll
    for (int j = 0; j < 4; ++j)
      async_copy16(W + (size_t)(srow + j * 64) * K + k0 + scol,
                   &Ws[(w * 8 + j * 64) * 64]);
    __syncthreads();
#pragma unroll
    for (int kk = 0; kk < 2; ++kk) {
      bf16x8 af[4], bfr[4];
#pragma unroll
      for (int f = 0; f < 4; ++f) {
        af[f]  = *(const bf16x8*)&As[(wm + f * 16 + c) * 64 + kk * 32 + g * 8];
        bfr[f] = *(const bf16x8*)&Ws[(wn + f * 16 + c) * 64 + kk * 32 + g * 8];
      }
#pragma unroll
      for (int fi = 0; fi < 4; ++fi)
#pragma unroll
        for (int fj = 0; fj < 4; ++fj)
          acc[fi][fj] = __builtin_amdgcn_mfma_f32_16x16x32_bf16(
              af[fi], bfr[fj], acc[fi][fj], 0, 0, 0);
    }
    __syncthreads();
  }

  float bv[4];
#pragma unroll
  for (int fj = 0; fj < 4; ++fj) bv[fj] = bias[wn + fj * 16 + c];
#pragma unroll
  for (int fi = 0; fi < 4; ++fi)
#pragma unroll
    for (int fj = 0; fj < 4; ++fj)
#pragma unroll
      for (int r2 = 0; r2 < 4; ++r2) acc[fi][fj][r2] += bv[fj];

#pragma unroll
  for (int fi = 0; fi < 4; ++fi)
#pragma unroll
    for (int r2 = 0; r2 < 4; ++r2) {
      float m_ = -1e30f;
#pragma unroll
      for (int fj = 0; fj < 4; ++fj) m_ = fmaxf(m_, acc[fi][fj][r2]);
#pragma unroll
      for (int off = 1; off < 16; off <<= 1) m_ = fmaxf(m_, __shfl_xor(m_, off));
      if (c == 0) redm[wn >> 6][wm + fi * 16 + g * 4 + r2] = m_;
    }
  __syncthreads();
  float mr[4][4];
#pragma unroll
  for (int fi = 0; fi < 4; ++fi)
#pragma unroll
    for (int r2 = 0; r2 < 4; ++r2) {
      int row = wm + fi * 16 + g * 4 + r2;
      float m4 = fmaxf(fmaxf(redm[0][row], redm[1][row]),
                       fmaxf(redm[2][row], redm[3][row]));
      mr[fi][r2] = m4;
      float z_ = 0.f, sx_ = 0.f;
#pragma unroll
      for (int fj = 0; fj < 4; ++fj) {
        float x = acc[fi][fj][r2];
        float e = __expf(x - m4);
        z_ += e; sx_ += e * x;
      }
#pragma unroll
      for (int off = 1; off < 16; off <<= 1) {
        z_ += __shfl_xor(z_, off);
        sx_ += __shfl_xor(sx_, off);
      }
      if (c == 0) {
        redz[wn >> 6][row] = z_;
        redx[wn >> 6][row] = sx_;
      }
    }
  __syncthreads();
  if ((w & 3) == 0 && c == 0) {
#pragma unroll
    for (int fi = 0; fi < 4; ++fi)
#pragma unroll
      for (int r2 = 0; r2 < 4; ++r2) {
        int row = wm + fi * 16 + g * 4 + r2;
        float Z = (redz[0][row] + redz[1][row]) + (redz[2][row] + redz[3][row]);
        float SX = (redx[0][row] + redx[1][row]) + (redx[2][row] + redx[3][row]);
        ent[m0 + row] = mr[fi][r2] + logf(Z) - SX / Z;
      }
  }
}

// ---------------------------------------------------------------------------
// MFMA flash attention, register-resident P.  Q pre-scaled by scale*log2e.
// One block (512 thr = 8 waves) per (batch, head).
// ---------------------------------------------------------------------------
__global__ __launch_bounds__(512, 4) void attn_mfma(
    const unsigned short* __restrict__ qkv, unsigned short* __restrict__ obf) {
  __shared__ __bf16 Ks[512 * 40];
  __shared__ __bf16 Vt[32 * 520];

  const int hh = blockIdx.x & 3, bl = blockIdx.x >> 2;
  const int t = threadIdx.x;
  const int lane = t & 63, wv = t >> 6;
  const int c = lane & 15, g = lane >> 4;
  const size_t tok0 = (size_t)bl * 512;

  {
    const unsigned short* kr = qkv + (tok0 + t) * 384 + 128 + hh * 32;
    bf16x8 k0 = *(const bf16x8*)(kr);
    bf16x8 k1 = *(const bf16x8*)(kr + 8);
    bf16x8 k2 = *(const bf16x8*)(kr + 16);
    bf16x8 k3 = *(const bf16x8*)(kr + 24);
    __bf16* kd = Ks + t * 40;
    *(bf16x8*)(kd + 0) = k0;  *(bf16x8*)(kd + 8) = k1;
    *(bf16x8*)(kd + 16) = k2; *(bf16x8*)(kd + 24) = k3;
    const unsigned short* vr = kr + 128;
    bf16x8 v0 = *(const bf16x8*)(vr);
    bf16x8 v1 = *(const bf16x8*)(vr + 8);
    bf16x8 v2 = *(const bf16x8*)(vr + 16);
    bf16x8 v3 = *(const bf16x8*)(vr + 24);
#pragma unroll
    for (int i = 0; i < 8; ++i) {
      Vt[(i)      * 520 + t] = v0[i];
      Vt[(i + 8)  * 520 + t] = v1[i];
      Vt[(i + 16) * 520 + t] = v2[i];
      Vt[(i + 24) * 520 + t] = v3[i];
    }
  }

  bf16x8 qb[4];
  {
    const unsigned short* qp = qkv + (tok0 + wv * 64) * 384 + hh * 32;
#pragma unroll
    for (int qf = 0; qf < 4; ++qf)
      qb[qf] = *(const bf16x8*)(qp + (size_t)(qf * 16 + c) * 384 + g * 8);
  }
  __syncthreads();

  f32x4 ot[4][2] = {};
  float l[4] = {0.f, 0.f, 0.f, 0.f};
  const f32x4 zz = {0.f, 0.f, 0.f, 0.f};

  for (int kt = 0; kt < 8; ++kt) {
    bf16x8 ka[4];
#pragma unroll
    for (int kf = 0; kf < 4; ++kf)
      ka[kf] = *(const bf16x8*)&Ks[(kt * 64 + kf * 16 + c) * 40 + g * 8];
    bf16x8 vb[2][2];
#pragma unroll
    for (int hf = 0; hf < 2; ++hf)
#pragma unroll
      for (int ksl = 0; ksl < 2; ++ksl)
        vb[hf][ksl] =
            *(const bf16x8*)&Vt[(hf * 16 + c) * 520 + kt * 64 + ksl * 32 + g * 8];

#pragma unroll
    for (int qf = 0; qf < 4; ++qf) {
      f32x4 sA = __builtin_amdgcn_mfma_f32_16x16x32_bf16(ka[0], qb[qf], zz, 0, 0, 0);
      f32x4 sB = __builtin_amdgcn_mfma_f32_16x16x32_bf16(ka[1], qb[qf], zz, 0, 0, 0);
      f32x4 sC = __builtin_amdgcn_mfma_f32_16x16x32_bf16(ka[2], qb[qf], zz, 0, 0, 0);
      f32x4 sD = __builtin_amdgcn_mfma_f32_16x16x32_bf16(ka[3], qb[qf], zz, 0, 0, 0);

      {
        float pa0 = EXP2(sA[0]), pa1 = EXP2(sA[1]);
        float pa2 = EXP2(sA[2]), pa3 = EXP2(sA[3]);
        float pb0 = EXP2(sB[0]), pb1 = EXP2(sB[1]);
        float pb2 = EXP2(sB[2]), pb3 = EXP2(sB[3]);
        l[qf] += ((pa0 + pa1) + (pa2 + pa3)) + ((pb0 + pb1) + (pb2 + pb3));
        unsigned int w00 = cvtpk_bf16(pa0, pa1), w01 = cvtpk_bf16(pa2, pa3);
        unsigned int w10 = cvtpk_bf16(pb0, pb1), w11 = cvtpk_bf16(pb2, pb3);
        plswap32(w00, w10); plswap16(w00, w10);
        plswap32(w01, w11); plswap16(w01, w11);
        union { unsigned int u[4]; bf16x8 v; } pk;
        pk.u[0] = w00; pk.u[1] = w01; pk.u[2] = w10; pk.u[3] = w11;
        ot[qf][0] = __builtin_amdgcn_mfma_f32_16x16x32_bf16(vb[0][0], pk.v,
                                                            ot[qf][0], 0, 0, 0);
        ot[qf][1] = __builtin_amdgcn_mfma_f32_16x16x32_bf16(vb[1][0], pk.v,
                                                            ot[qf][1], 0, 0, 0);
      }
      {
        float pa0 = EXP2(sC[0]), pa1 = EXP2(sC[1]);
        float pa2 = EXP2(sC[2]), pa3 = EXP2(sC[3]);
        float pb0 = EXP2(sD[0]), pb1 = EXP2(sD[1]);
        float pb2 = EXP2(sD[2]), pb3 = EXP2(sD[3]);
        l[qf] += ((pa0 + pa1) + (pa2 + pa3)) + ((pb0 + pb1) + (pb2 + pb3));
        unsigned int w00 = cvtpk_bf16(pa0, pa1), w01 = cvtpk_bf16(pa2, pa3);
        unsigned int w10 = cvtpk_bf16(pb0, pb1), w11 = cvtpk_bf16(pb2, pb3);
        plswap32(w00, w10); plswap16(w00, w10);
        plswap32(w01, w11); plswap16(w01, w11);
        union { unsigned int u[4]; bf16x8 v; } pk;
        pk.u[0] = w00; pk.u[1] = w01; pk.u[2] = w10; pk.u[3] = w11;
        ot[qf][0] = __builtin_amdgcn_mfma_f32_16x16x32_bf16(vb[0][1], pk.v,
                                                            ot[qf][0], 0, 0, 0);
        ot[qf][1] = __builtin_amdgcn_mfma_f32_16x16x32_bf16(vb[1][1], pk.v,
                                                            ot[qf][1], 0, 0, 0);
      }
    }
  }

#pragma unroll
  for (int qf = 0; qf < 4; ++qf) {
    l[qf] += __shfl_xor(l[qf], 16);
    l[qf] += __shfl_xor(l[qf], 32);
  }
#pragma unroll
  for (int qf = 0; qf < 4; ++qf) {
    float rl = 1.0f / l[qf];
#pragma unroll
    for (int hf = 0; hf < 2; ++hf) {
      ushort4 pk;
      pk.x = f2bf(ot[qf][hf][0] * rl);
      pk.y = f2bf(ot[qf][hf][1] * rl);
      pk.z = f2bf(ot[qf][hf][2] * rl);
      pk.w = f2bf(ot[qf][hf][3] * rl);
      *(ushort4*)(obf + (tok0 + wv * 64 + qf * 16 + c) * 128 + hh * 32 +
                  hf * 16 + g * 4) = pk;
    }
  }
}

// ---------------------------------------------------------------------------
__global__ __launch_bounds__(64) void avg_entropy_kernel(
    const float* __restrict__ ent, float* __restrict__ out) {
  int s = blockIdx.x, lane = threadIdx.x;
  float a = 0.f;
  for (int b = lane; b < 256; b += 64) a += ent[(size_t)b * 512 + s];
#pragma unroll
  for (int off = 32; off; off >>= 1) a += __shfl_xor(a, off);
  if (lane == 0) out[s] = a * 0.00390625f;
}

__global__ __launch_bounds__(512) void seg_kernel(float* out) {
  __shared__ int cs[512];
  int i = threadIdx.x;
  float e = out[i];
  cs[i] = (i >= 1 && e > 4.0f) ? 1 : 0;
  __syncthreads();
  for (int off = 1; off < 512; off <<= 1) {
    int v = (i >= off) ? cs[i - off] : 0;
    __syncthreads();
    cs[i] += v;
    __syncthreads();
  }
  out[512 + i] = (float)cs[i];
}

// ---------------------------------------------------------------------------
extern "C" void kernel_launch(void* const* d_in, const int* in_sizes, int n_in,
                              void* d_out, int out_size, void* d_ws,
                              size_t ws_size, hipStream_t stream) {
  (void)in_sizes; (void)n_in; (void)out_size; (void)ws_size;
  const int*   input_bytes = (const int*)d_in[0];
  const float* emb    = (const float*)d_in[1];
  const float* pos    = (const float*)d_in[2];
  const float* ln_g   = (const float*)d_in[3];
  const float* ln_b   = (const float*)d_in[4];
  const float* attn_w = (const float*)d_in[5];
  const float* attn_b = (const float*)d_in[6];
  const float* out_w  = (const float*)d_in[7];
  const float* out_b  = (const float*)d_in[8];
  const float* ff1_w  = (const float*)d_in[9];
  const float* ff1_b  = (const float*)d_in[10];
  const float* ff2_w  = (const float*)d_in[11];
  const float* ff2_b  = (const float*)d_in[12];
  const float* n1_g   = (const float*)d_in[13];
  const float* n1_b   = (const float*)d_in[14];
  const float* n2_g   = (const float*)d_in[15];
  const float* n2_b   = (const float*)d_in[16];
  const float* proj_w = (const float*)d_in[17];
  const float* proj_b = (const float*)d_in[18];

  char* ws = (char*)d_ws;
  unsigned short* hbf  = (unsigned short*)(ws);                // 32 MB
  unsigned short* obf  = (unsigned short*)(ws + 33554432);     // 32 MB
  unsigned short* qkvc = (unsigned short*)(ws + 67108864);     // 96 MB
  unsigned short* wbf  = (unsigned short*)(ws + 167772160);    // ~0.85 MB
  float*          absb = (float*)(ws + 168624128);             // 3 KB
  float*          entb = (float*)(ws + 168628224);             // 0.5 MB

  unsigned short* attnw_bf = wbf;
  unsigned short* outw_bf  = wbf + 98304;
  unsigned short* w1p      = wbf + 131072;
  unsigned short* w2p      = wbf + 262144;
  unsigned short* projw_bf = wbf + 393216;

  conv_attn_w<<<384, 256, 0, stream>>>(attn_w, attnw_bf);
  conv_attn_b<<<3, 256, 0, stream>>>(attn_b, absb);
  f32_to_bf16<<<128, 256, 0, stream>>>(out_w, outw_bf, 32768);
  conv_perm<<<512, 256, 0, stream>>>(ff1_w, w1p, 128, 131072);
  conv_perm<<<512, 256, 0, stream>>>(ff2_w, w2p, 512, 131072);
  f32_to_bf16<<<128, 256, 0, stream>>>(proj_w, projw_bf, 32768);

  embed_ln<<<32768, 256, 0, stream>>>(input_bytes, emb, pos, ln_g, ln_b, hbf);

  for (int l = 0; l < 2; ++l) {
    // QKV GEMM (bf16 out, Q pre-scaled) full M, then attention full batch
    gemm_bf16<0, 1><<<dim3(3, 1024), 256, 0, stream>>>(
        hbf, attnw_bf + l * 49152, absb + l * 384, qkvc, 131072, 384, 128);
    attn_mfma<<<1024, 512, 0, stream>>>(qkvc, obf);
    // fused out-proj + residual + LN1 (in place on hbf)
    gemm_ln_res<<<1024, 256, 0, stream>>>(
        obf, outw_bf + l * 16384, out_b + l * 128, hbf,
        n1_g + l * 128, n1_b + l * 128, hbf, 131072, 128);
    // fused FFN + residual + LN2 (in place on hbf)
    ffn_fused<<<1024, 512, 0, stream>>>(
        hbf, w1p + l * 65536, ff1_b + l * 512, w2p + l * 65536,
        ff2_b + l * 128, n2_g + l * 128, n2_b + l * 128, hbf);
  }

  // fused vocab projection + entropy
  gemm_entropy<<<1024, 512, 0, stream>>>(hbf, projw_bf, proj_b, entb, 128);
  avg_entropy_kernel<<<512, 64, 0, stream>>>(entb, (float*)d_out);
  seg_kernel<<<1, 512, 0, stream>>>((float*)d_out);
}

// Round 6
// 550.040 us; speedup vs baseline: 1.6477x; 1.0008x over previous
//
#include <hip/hip_runtime.h>

// ---------------------------------------------------------------------------
// EntropyCalculator: 2-layer post-norm transformer encoder + entropy head.
// B=256 S=512 D=128 H=4 HD=32 FF=512 V=256
// bf16 residual stream; fused FFN (XOR-swizzled LDS); fused GEMM+LN and
// GEMM+entropy epilogues; register-P MFMA flash attention.
// ---------------------------------------------------------------------------

#define AS1 __attribute__((address_space(1)))
#define AS3 __attribute__((address_space(3)))

typedef __bf16 bf16x8 __attribute__((ext_vector_type(8)));
typedef __bf16 bf16x4 __attribute__((ext_vector_type(4)));
typedef float  f32x4  __attribute__((ext_vector_type(4)));

__device__ __forceinline__ unsigned short f2bf(float f) {
  union { float f; unsigned int u; } c; c.f = f;
  unsigned int u = c.u;
  u += 0x7FFFu + ((u >> 16) & 1u);   // round-to-nearest-even
  return (unsigned short)(u >> 16);
}
__device__ __forceinline__ float bf2f(unsigned short u) {
  union { unsigned int u; float f; } c; c.u = ((unsigned int)u) << 16;
  return c.f;
}

__device__ __forceinline__ float EXP2(float x) {
#if __has_builtin(__builtin_amdgcn_exp2f)
  return __builtin_amdgcn_exp2f(x);
#else
  return exp2f(x);
#endif
}

__device__ __forceinline__ void async_copy16(const void* g, void* l) {
  __builtin_amdgcn_global_load_lds((AS1 void*)(void*)g, (AS3 void*)l, 16, 0, 0);
}

__device__ __forceinline__ unsigned int cvtpk_bf16(float lo, float hi) {
  unsigned int r;
  asm("v_cvt_pk_bf16_f32 %0, %1, %2" : "=v"(r) : "v"(lo), "v"(hi));
  return r;
}
__device__ __forceinline__ void plswap32(unsigned int& a, unsigned int& b) {
  asm("v_permlane32_swap_b32 %0, %1" : "+v"(a), "+v"(b));
}
__device__ __forceinline__ void plswap16(unsigned int& a, unsigned int& b) {
  asm("v_permlane16_swap_b32 %0, %1" : "+v"(a), "+v"(b));
}

// ---------------------------------------------------------------------------
// weight conversions
// ---------------------------------------------------------------------------
__global__ void f32_to_bf16(const float* __restrict__ src,
                            unsigned short* __restrict__ dst, int n) {
  int i = blockIdx.x * blockDim.x + threadIdx.x;
  if (i < n) dst[i] = f2bf(src[i]);
}

// Permute a [N][K] weight into MFMA-B-fragment lane order:
// dst[(row>>4)*(16K) + (k>>5)*512 + (row&15)*32 + (k&31)]
__global__ void conv_perm(const float* __restrict__ src,
                          unsigned short* __restrict__ dst, int K, int n) {
  int i = blockIdx.x * 256 + threadIdx.x;
  if (i >= n) return;
  int l = i >> 16, rem = i & 65535;            // perLayer = 65536
  int row = rem / K, k = rem - row * K;
  int d = (row >> 4) * (K * 16) + (k >> 5) * 512 + (row & 15) * 32 + (k & 31);
  dst[(l << 16) + d] = f2bf(src[i]);
}

// attn_w with Q rows pre-scaled by (1/sqrt(HD))*log2(e)
#define QSCALE 0.2550602989892646f
__global__ void conv_attn_w(const float* __restrict__ src,
                            unsigned short* __restrict__ dst) {
  int i = blockIdx.x * 256 + threadIdx.x;  // 98304
  int r = (i >> 7) % 384;
  float v = src[i];
  if (r < 128) v *= QSCALE;
  dst[i] = f2bf(v);
}
__global__ void conv_attn_b(const float* __restrict__ src,
                            float* __restrict__ dst) {
  int i = blockIdx.x * 256 + threadIdx.x;  // 768
  if (i < 768) {
    float v = src[i];
    if ((i % 384) < 128) v *= QSCALE;
    dst[i] = v;
  }
}

// ---------------------------------------------------------------------------
// Embedding + LayerNorm -> bf16 residual stream.  One wave per token.
// ---------------------------------------------------------------------------
__global__ __launch_bounds__(256) void embed_ln(
    const int* __restrict__ bytes, const float* __restrict__ emb,
    const float* __restrict__ pos, const float* __restrict__ g,
    const float* __restrict__ bta, unsigned short* __restrict__ hbf) {
  int wv = threadIdx.x >> 6, lane = threadIdx.x & 63;
  int tok = blockIdx.x * 4 + wv;
  int s = tok & 511;
  int bidx = bytes[tok];
  const float* e = emb + (size_t)bidx * 128;
  const float* p = pos + (size_t)s * 128;
  float x0 = e[lane] + p[lane];
  float x1 = e[lane + 64] + p[lane + 64];
  float sum = x0 + x1, ssq = x0 * x0 + x1 * x1;
#pragma unroll
  for (int off = 32; off; off >>= 1) {
    sum += __shfl_xor(sum, off);
    ssq += __shfl_xor(ssq, off);
  }
  float mean = sum * 0.0078125f;
  float var = ssq * 0.0078125f - mean * mean;
  float rs = rsqrtf(var + 1e-5f);
  float y0 = (x0 - mean) * rs * g[lane] + bta[lane];
  float y1 = (x1 - mean) * rs * g[lane + 64] + bta[lane + 64];
  size_t o = (size_t)tok * 128;
  hbf[o + lane] = f2bf(y0); hbf[o + lane + 64] = f2bf(y1);
}

// ---------------------------------------------------------------------------
// bf16 MFMA GEMM:  C[M,N] = A[M,K] @ W[N,K]^T + bias  (bf16 out option)
// 128x128 tile, BK=64, 4 waves.
// ---------------------------------------------------------------------------
template <int RELU, int OUTBF>
__global__ __launch_bounds__(256) void gemm_bf16(
    const unsigned short* __restrict__ A, const unsigned short* __restrict__ W,
    const float* __restrict__ bias, void* __restrict__ Cout,
    int M, int N, int K) {
  __shared__ __bf16 As[128 * 64];
  __shared__ __bf16 Ws[128 * 64];
  const int t = threadIdx.x;
  const int lane = t & 63, w = t >> 6;
  const int m0 = blockIdx.y * 128, n0 = blockIdx.x * 128;
  const int wm = (w >> 1) * 64, wn = (w & 1) * 64;
  f32x4 acc[4][4] = {};
  const int srow = w * 32 + (lane >> 3);
  const int scol = (lane & 7) * 8;

  for (int k0 = 0; k0 < K; k0 += 64) {
#pragma unroll
    for (int j = 0; j < 4; ++j) {
      int r = srow + j * 8;
      int ldsrow = w * 32 + j * 8;
      async_copy16(A + (size_t)(m0 + r) * K + k0 + scol, &As[ldsrow * 64]);
      async_copy16(W + (size_t)(n0 + r) * K + k0 + scol, &Ws[ldsrow * 64]);
    }
    __syncthreads();
#pragma unroll
    for (int kk = 0; kk < 2; ++kk) {
      bf16x8 af[4], bfr[4];
#pragma unroll
      for (int f = 0; f < 4; ++f) {
        af[f]  = *(const bf16x8*)&As[(wm + f * 16 + (lane & 15)) * 64 + kk * 32 + (lane >> 4) * 8];
        bfr[f] = *(const bf16x8*)&Ws[(wn + f * 16 + (lane & 15)) * 64 + kk * 32 + (lane >> 4) * 8];
      }
#pragma unroll
      for (int fi = 0; fi < 4; ++fi)
#pragma unroll
        for (int fj = 0; fj < 4; ++fj)
          acc[fi][fj] = __builtin_amdgcn_mfma_f32_16x16x32_bf16(
              af[fi], bfr[fj], acc[fi][fj], 0, 0, 0);
    }
    __syncthreads();
  }

#pragma unroll
  for (int fj = 0; fj < 4; ++fj) {
    int col = n0 + wn + fj * 16 + (lane & 15);
    float bv = bias[col];
#pragma unroll
    for (int fi = 0; fi < 4; ++fi) {
#pragma unroll
      for (int r2 = 0; r2 < 4; ++r2) {
        int row = m0 + wm + fi * 16 + (lane >> 4) * 4 + r2;
        float v = acc[fi][fj][r2] + bv;
        if (RELU) v = fmaxf(v, 0.0f);
        if (OUTBF)
          ((unsigned short*)Cout)[(size_t)row * N + col] = f2bf(v);
        else
          ((float*)Cout)[(size_t)row * N + col] = v;
      }
    }
  }
}

// ---------------------------------------------------------------------------
// Fused GEMM (N=128) + residual add + LayerNorm -> bf16 (in-place on res ok).
// ---------------------------------------------------------------------------
__global__ __launch_bounds__(256) void gemm_ln_res(
    const unsigned short* __restrict__ A, const unsigned short* __restrict__ W,
    const float* __restrict__ bias, const unsigned short* __restrict__ res,
    const float* __restrict__ gamma, const float* __restrict__ beta,
    unsigned short* __restrict__ out, int M, int K) {
  __shared__ __bf16 As[128 * 64];
  __shared__ __bf16 Ws[128 * 64];
  __shared__ float red[2][128][2];
  const int t = threadIdx.x;
  const int lane = t & 63, w = t >> 6;
  const int m0 = blockIdx.x * 128;
  const int wm = (w >> 1) * 64, wn = (w & 1) * 64;
  const int c = lane & 15, g = lane >> 4;
  f32x4 acc[4][4] = {};
  const int srow = w * 32 + (lane >> 3);
  const int scol = (lane & 7) * 8;

  for (int k0 = 0; k0 < K; k0 += 64) {
#pragma unroll
    for (int j = 0; j < 4; ++j) {
      int r = srow + j * 8;
      int ldsrow = w * 32 + j * 8;
      async_copy16(A + (size_t)(m0 + r) * K + k0 + scol, &As[ldsrow * 64]);
      async_copy16(W + (size_t)(r) * K + k0 + scol, &Ws[ldsrow * 64]);
    }
    __syncthreads();
#pragma unroll
    for (int kk = 0; kk < 2; ++kk) {
      bf16x8 af[4], bfr[4];
#pragma unroll
      for (int f = 0; f < 4; ++f) {
        af[f]  = *(const bf16x8*)&As[(wm + f * 16 + c) * 64 + kk * 32 + g * 8];
        bfr[f] = *(const bf16x8*)&Ws[(wn + f * 16 + c) * 64 + kk * 32 + g * 8];
      }
#pragma unroll
      for (int fi = 0; fi < 4; ++fi)
#pragma unroll
        for (int fj = 0; fj < 4; ++fj)
          acc[fi][fj] = __builtin_amdgcn_mfma_f32_16x16x32_bf16(
              af[fi], bfr[fj], acc[fi][fj], 0, 0, 0);
    }
    __syncthreads();
  }

  float bv[4], gl[4], bl[4];
#pragma unroll
  for (int fj = 0; fj < 4; ++fj) {
    bv[fj] = bias[wn + fj * 16 + c];
    gl[fj] = gamma[wn + fj * 16 + c];
    bl[fj] = beta[wn + fj * 16 + c];
  }
#pragma unroll
  for (int fi = 0; fi < 4; ++fi)
#pragma unroll
    for (int r2 = 0; r2 < 4; ++r2) {
      int row = wm + fi * 16 + g * 4 + r2;
      const unsigned short* rr = res + (size_t)(m0 + row) * 128;
#pragma unroll
      for (int fj = 0; fj < 4; ++fj)
        acc[fi][fj][r2] += bv[fj] + bf2f(rr[wn + fj * 16 + c]);
    }
#pragma unroll
  for (int fi = 0; fi < 4; ++fi)
#pragma unroll
    for (int r2 = 0; r2 < 4; ++r2) {
      float s_ = 0.f, q_ = 0.f;
#pragma unroll
      for (int fj = 0; fj < 4; ++fj) {
        float x = acc[fi][fj][r2];
        s_ += x; q_ += x * x;
      }
#pragma unroll
      for (int off = 1; off < 16; off <<= 1) {
        s_ += __shfl_xor(s_, off);
        q_ += __shfl_xor(q_, off);
      }
      if (c == 0) {
        int row = wm + fi * 16 + g * 4 + r2;
        red[wn >> 6][row][0] = s_;
        red[wn >> 6][row][1] = q_;
      }
    }
  __syncthreads();
#pragma unroll
  for (int fi = 0; fi < 4; ++fi)
#pragma unroll
    for (int r2 = 0; r2 < 4; ++r2) {
      int row = wm + fi * 16 + g * 4 + r2;
      float s_ = red[0][row][0] + red[1][row][0];
      float q_ = red[0][row][1] + red[1][row][1];
      float mean = s_ * 0.0078125f;
      float var = q_ * 0.0078125f - mean * mean;
      float rs = rsqrtf(var + 1e-5f);
      unsigned short* orow = out + (size_t)(m0 + row) * 128;
#pragma unroll
      for (int fj = 0; fj < 4; ++fj) {
        float y = (acc[fi][fj][r2] - mean) * rs * gl[fj] + bl[fj];
        orow[wn + fj * 16 + c] = f2bf(y);
      }
    }
}

// ---------------------------------------------------------------------------
// Fused FFN: out = LN(res + b2 + relu(res @ W1^T + b1) @ W2^T).
// One block = 128 tokens, 512 thr (8 waves as 2x4).
// A and G tiles in LDS with 16B-chunk XOR swizzle: chunk ^= (row & 15).
// A staged via global_load_lds with PRE-SWIZZLED global source (linear dest).
// W1/W2 read directly from L2 in pre-permuted fragment order (conv_perm).
// ---------------------------------------------------------------------------
__global__ __launch_bounds__(512, 4) void ffn_fused(
    const unsigned short* __restrict__ hin,
    const unsigned short* __restrict__ W1p, const float* __restrict__ b1,
    const unsigned short* __restrict__ W2p, const float* __restrict__ b2,
    const float* __restrict__ gamma, const float* __restrict__ beta,
    unsigned short* __restrict__ out) {
  __shared__ __bf16 As[128 * 128];
  __shared__ __bf16 Gs[128 * 128];
  __shared__ float red[4][128][2];
  const int t = threadIdx.x;
  const int lane = t & 63, w = t >> 6;
  const int c = lane & 15, g = lane >> 4;
  const int wm = (w >> 2) * 64;        // token-row group
  const int wn = (w & 3) * 32;         // col group
  const size_t m0 = (size_t)blockIdx.x * 128;
  const int lidx = (c * 4 + g) * 8;    // lane offset into permuted W frag

  // stage A tile: linear LDS dest, pre-swizzled global source
  {
    const unsigned short* Ab = hin + m0 * 128;
#pragma unroll
    for (int j = 0; j < 4; ++j) {
      int gi = j * 512 + t;            // dest granule index (16B units)
      int row = gi >> 4, ch = gi & 15;
      int sch = ch ^ (row & 15);       // inverse swizzle on source
      char* ldsbase = (char*)As + (j * 512 + w * 64) * 16;
      async_copy16(Ab + (size_t)row * 128 + sch * 8, ldsbase);
    }
  }
  __syncthreads();

  f32x4 acc2[4][2] = {};
  for (int f = 0; f < 4; ++f) {
    // ---- gemm1 chunk: G_f = relu(A @ W1_f^T + b1_f) ----
    f32x4 acc1[4][2] = {};
    const unsigned short* w1b = W1p + (f * 8 + (w & 3) * 2) * 2048;
#pragma unroll
    for (int kk = 0; kk < 4; ++kk) {
      bf16x8 af[4];
#pragma unroll
      for (int fi = 0; fi < 4; ++fi) {
        int row = wm + fi * 16 + c;                 // row & 15 == c
        int ch = (kk * 4 + g) ^ c;                  // swizzled chunk
        af[fi] = *(const bf16x8*)((char*)As + row * 256 + ch * 16);
      }
#pragma unroll
      for (int fj = 0; fj < 2; ++fj) {
        bf16x8 bw = *(const bf16x8*)(w1b + fj * 2048 + kk * 512 + lidx);
#pragma unroll
        for (int fi = 0; fi < 4; ++fi)
          acc1[fi][fj] = __builtin_amdgcn_mfma_f32_16x16x32_bf16(
              af[fi], bw, acc1[fi][fj], 0, 0, 0);
      }
    }
    float bv1[2] = {b1[f * 128 + wn + c], b1[f * 128 + wn + 16 + c]};
#pragma unroll
    for (int fi = 0; fi < 4; ++fi)
#pragma unroll
      for (int fj = 0; fj < 2; ++fj)
#pragma unroll
        for (int r = 0; r < 4; ++r) {
          int row = wm + fi * 16 + g * 4 + r;
          int col = wn + fj * 16 + c;
          int ch = (col >> 3) ^ (row & 15);
          float v = fmaxf(acc1[fi][fj][r] + bv1[fj], 0.0f);
          *(unsigned short*)((char*)Gs + row * 256 + ch * 16 + (col & 7) * 2) =
              f2bf(v);
        }
    __syncthreads();
    // ---- gemm2 partial: acc2 += G_f @ W2_f^T ----
    const unsigned short* w2b = W2p + ((w & 3) * 2) * 8192 + f * 2048;
#pragma unroll
    for (int kk = 0; kk < 4; ++kk) {
      bf16x8 gf[4];
#pragma unroll
      for (int fi = 0; fi < 4; ++fi) {
        int row = wm + fi * 16 + c;
        int ch = (kk * 4 + g) ^ c;
        gf[fi] = *(const bf16x8*)((char*)Gs + row * 256 + ch * 16);
      }
#pragma unroll
      for (int fj = 0; fj < 2; ++fj) {
        bf16x8 bw = *(const bf16x8*)(w2b + fj * 8192 + kk * 512 + lidx);
#pragma unroll
        for (int fi = 0; fi < 4; ++fi)
          acc2[fi][fj] = __builtin_amdgcn_mfma_f32_16x16x32_bf16(
              gf[fi], bw, acc2[fi][fj], 0, 0, 0);
      }
    }
    __syncthreads();
  }

  // ---- epilogue: bias + residual + LayerNorm ----
  float bv2[2] = {b2[wn + c], b2[wn + 16 + c]};
  float xv[4][2][4];
#pragma unroll
  for (int fi = 0; fi < 4; ++fi)
#pragma unroll
    for (int r = 0; r < 4; ++r) {
      int row = wm + fi * 16 + g * 4 + r;
#pragma unroll
      for (int fj = 0; fj < 2; ++fj) {
        int col = wn + fj * 16 + c;
        int ch = (col >> 3) ^ (row & 15);
        float res = bf2f(*(const unsigned short*)((char*)As + row * 256 +
                                                  ch * 16 + (col & 7) * 2));
        xv[fi][fj][r] = acc2[fi][fj][r] + bv2[fj] + res;
      }
    }
#pragma unroll
  for (int fi = 0; fi < 4; ++fi)
#pragma unroll
    for (int r = 0; r < 4; ++r) {
      float a0 = xv[fi][0][r], a1 = xv[fi][1][r];
      float s_ = a0 + a1, q_ = a0 * a0 + a1 * a1;
#pragma unroll
      for (int off = 1; off < 16; off <<= 1) {
        s_ += __shfl_xor(s_, off);
        q_ += __shfl_xor(q_, off);
      }
      if (c == 0) {
        int row = wm + fi * 16 + g * 4 + r;
        red[w & 3][row][0] = s_;
        red[w & 3][row][1] = q_;
      }
    }
  __syncthreads();
  float gl[2] = {gamma[wn + c], gamma[wn + 16 + c]};
  float bl[2] = {beta[wn + c], beta[wn + 16 + c]};
#pragma unroll
  for (int fi = 0; fi < 4; ++fi)
#pragma unroll
    for (int r = 0; r < 4; ++r) {
      int row = wm + fi * 16 + g * 4 + r;
      float s_ = (red[0][row][0] + red[1][row][0]) + (red[2][row][0] + red[3][row][0]);
      float q_ = (red[0][row][1] + red[1][row][1]) + (red[2][row][1] + red[3][row][1]);
      float mean = s_ * 0.0078125f;
      float var = q_ * 0.0078125f - mean * mean;
      float rs = rsqrtf(var + 1e-5f);
#pragma unroll
      for (int fj = 0; fj < 2; ++fj) {
        float y = (xv[fi][fj][r] - mean) * rs * gl[fj] + bl[fj];
        out[(m0 + row) * 128 + wn + fj * 16 + c] = f2bf(y);
      }
    }
}

// ---------------------------------------------------------------------------
// Fused vocab GEMM (N=256) + entropy.  Tile 128x256, 8 waves (512 thr).
// ---------------------------------------------------------------------------
__global__ __launch_bounds__(512) void gemm_entropy(
    const unsigned short* __restrict__ A, const unsigned short* __restrict__ W,
    const float* __restrict__ bias, float* __restrict__ ent, int K) {
  __shared__ __bf16 As[128 * 64];
  __shared__ __bf16 Ws[256 * 64];
  __shared__ float redm[4][128], redz[4][128], redx[4][128];
  const int t = threadIdx.x;
  const int lane = t & 63, w = t >> 6;
  const int m0 = blockIdx.x * 128;
  const int wm = (w >> 2) * 64, wn = (w & 3) * 64;
  const int c = lane & 15, g = lane >> 4;
  f32x4 acc[4][4] = {};
  const int srow = w * 8 + (lane >> 3);
  const int scol = (lane & 7) * 8;

  for (int k0 = 0; k0 < K; k0 += 64) {
#pragma unroll
    for (int j = 0; j < 2; ++j)
      async_copy16(A + (size_t)(m0 + srow + j * 64) * K + k0 + scol,
                   &As[(w * 8 + j * 64) * 64]);
#pragma unroll
    for (int j = 0; j < 4; ++j)
      async_copy16(W + (size_t)(srow + j * 64) * K + k0 + scol,
                   &Ws[(w * 8 + j * 64) * 64]);
    __syncthreads();
#pragma unroll
    for (int kk = 0; kk < 2; ++kk) {
      bf16x8 af[4], bfr[4];
#pragma unroll
      for (int f = 0; f < 4; ++f) {
        af[f]  = *(const bf16x8*)&As[(wm + f * 16 + c) * 64 + kk * 32 + g * 8];
        bfr[f] = *(const bf16x8*)&Ws[(wn + f * 16 + c) * 64 + kk * 32 + g * 8];
      }
#pragma unroll
      for (int fi = 0; fi < 4; ++fi)
#pragma unroll
        for (int fj = 0; fj < 4; ++fj)
          acc[fi][fj] = __builtin_amdgcn_mfma_f32_16x16x32_bf16(
              af[fi], bfr[fj], acc[fi][fj], 0, 0, 0);
    }
    __syncthreads();
  }

  float bv[4];
#pragma unroll
  for (int fj = 0; fj < 4; ++fj) bv[fj] = bias[wn + fj * 16 + c];
#pragma unroll
  for (int fi = 0; fi < 4; ++fi)
#pragma unroll
    for (int fj = 0; fj < 4; ++fj)
#pragma unroll
      for (int r2 = 0; r2 < 4; ++r2) acc[fi][fj][r2] += bv[fj];

#pragma unroll
  for (int fi = 0; fi < 4; ++fi)
#pragma unroll
    for (int r2 = 0; r2 < 4; ++r2) {
      float m_ = -1e30f;
#pragma unroll
      for (int fj = 0; fj < 4; ++fj) m_ = fmaxf(m_, acc[fi][fj][r2]);
#pragma unroll
      for (int off = 1; off < 16; off <<= 1) m_ = fmaxf(m_, __shfl_xor(m_, off));
      if (c == 0) redm[wn >> 6][wm + fi * 16 + g * 4 + r2] = m_;
    }
  __syncthreads();
  float mr[4][4];
#pragma unroll
  for (int fi = 0; fi < 4; ++fi)
#pragma unroll
    for (int r2 = 0; r2 < 4; ++r2) {
      int row = wm + fi * 16 + g * 4 + r2;
      float m4 = fmaxf(fmaxf(redm[0][row], redm[1][row]),
                       fmaxf(redm[2][row], redm[3][row]));
      mr[fi][r2] = m4;
      float z_ = 0.f, sx_ = 0.f;
#pragma unroll
      for (int fj = 0; fj < 4; ++fj) {
        float x = acc[fi][fj][r2];
        float e = __expf(x - m4);
        z_ += e; sx_ += e * x;
      }
#pragma unroll
      for (int off = 1; off < 16; off <<= 1) {
        z_ += __shfl_xor(z_, off);
        sx_ += __shfl_xor(sx_, off);
      }
      if (c == 0) {
        redz[wn >> 6][row] = z_;
        redx[wn >> 6][row] = sx_;
      }
    }
  __syncthreads();
  if ((w & 3) == 0 && c == 0) {
#pragma unroll
    for (int fi = 0; fi < 4; ++fi)
#pragma unroll
      for (int r2 = 0; r2 < 4; ++r2) {
        int row = wm + fi * 16 + g * 4 + r2;
        float Z = (redz[0][row] + redz[1][row]) + (redz[2][row] + redz[3][row]);
        float SX = (redx[0][row] + redx[1][row]) + (redx[2][row] + redx[3][row]);
        ent[m0 + row] = mr[fi][r2] + logf(Z) - SX / Z;
      }
  }
}

// ---------------------------------------------------------------------------
// MFMA flash attention, register-resident P.  Q pre-scaled by scale*log2e.
// One block (512 thr = 8 waves) per (batch, head).
// ---------------------------------------------------------------------------
__global__ __launch_bounds__(512, 4) void attn_mfma(
    const unsigned short* __restrict__ qkv, unsigned short* __restrict__ obf) {
  __shared__ __bf16 Ks[512 * 40];
  __shared__ __bf16 Vt[32 * 520];

  const int hh = blockIdx.x & 3, bl = blockIdx.x >> 2;
  const int t = threadIdx.x;
  const int lane = t & 63, wv = t >> 6;
  const int c = lane & 15, g = lane >> 4;
  const size_t tok0 = (size_t)bl * 512;

  {
    const unsigned short* kr = qkv + (tok0 + t) * 384 + 128 + hh * 32;
    bf16x8 k0 = *(const bf16x8*)(kr);
    bf16x8 k1 = *(const bf16x8*)(kr + 8);
    bf16x8 k2 = *(const bf16x8*)(kr + 16);
    bf16x8 k3 = *(const bf16x8*)(kr + 24);
    __bf16* kd = Ks + t * 40;
    *(bf16x8*)(kd + 0) = k0;  *(bf16x8*)(kd + 8) = k1;
    *(bf16x8*)(kd + 16) = k2; *(bf16x8*)(kd + 24) = k3;
    const unsigned short* vr = kr + 128;
    bf16x8 v0 = *(const bf16x8*)(vr);
    bf16x8 v1 = *(const bf16x8*)(vr + 8);
    bf16x8 v2 = *(const bf16x8*)(vr + 16);
    bf16x8 v3 = *(const bf16x8*)(vr + 24);
#pragma unroll
    for (int i = 0; i < 8; ++i) {
      Vt[(i)      * 520 + t] = v0[i];
      Vt[(i + 8)  * 520 + t] = v1[i];
      Vt[(i + 16) * 520 + t] = v2[i];
      Vt[(i + 24) * 520 + t] = v3[i];
    }
  }

  bf16x8 qb[4];
  {
    const unsigned short* qp = qkv + (tok0 + wv * 64) * 384 + hh * 32;
#pragma unroll
    for (int qf = 0; qf < 4; ++qf)
      qb[qf] = *(const bf16x8*)(qp + (size_t)(qf * 16 + c) * 384 + g * 8);
  }
  __syncthreads();

  f32x4 ot[4][2] = {};
  float l[4] = {0.f, 0.f, 0.f, 0.f};
  const f32x4 zz = {0.f, 0.f, 0.f, 0.f};

  for (int kt = 0; kt < 8; ++kt) {
    bf16x8 ka[4];
#pragma unroll
    for (int kf = 0; kf < 4; ++kf)
      ka[kf] = *(const bf16x8*)&Ks[(kt * 64 + kf * 16 + c) * 40 + g * 8];
    bf16x8 vb[2][2];
#pragma unroll
    for (int hf = 0; hf < 2; ++hf)
#pragma unroll
      for (int ksl = 0; ksl < 2; ++ksl)
        vb[hf][ksl] =
            *(const bf16x8*)&Vt[(hf * 16 + c) * 520 + kt * 64 + ksl * 32 + g * 8];

#pragma unroll
    for (int qf = 0; qf < 4; ++qf) {
      f32x4 sA = __builtin_amdgcn_mfma_f32_16x16x32_bf16(ka[0], qb[qf], zz, 0, 0, 0);
      f32x4 sB = __builtin_amdgcn_mfma_f32_16x16x32_bf16(ka[1], qb[qf], zz, 0, 0, 0);
      f32x4 sC = __builtin_amdgcn_mfma_f32_16x16x32_bf16(ka[2], qb[qf], zz, 0, 0, 0);
      f32x4 sD = __builtin_amdgcn_mfma_f32_16x16x32_bf16(ka[3], qb[qf], zz, 0, 0, 0);

      {
        float pa0 = EXP2(sA[0]), pa1 = EXP2(sA[1]);
        float pa2 = EXP2(sA[2]), pa3 = EXP2(sA[3]);
        float pb0 = EXP2(sB[0]), pb1 = EXP2(sB[1]);
        float pb2 = EXP2(sB[2]), pb3 = EXP2(sB[3]);
        l[qf] += ((pa0 + pa1) + (pa2 + pa3)) + ((pb0 + pb1) + (pb2 + pb3));
        unsigned int w00 = cvtpk_bf16(pa0, pa1), w01 = cvtpk_bf16(pa2, pa3);
        unsigned int w10 = cvtpk_bf16(pb0, pb1), w11 = cvtpk_bf16(pb2, pb3);
        plswap32(w00, w10); plswap16(w00, w10);
        plswap32(w01, w11); plswap16(w01, w11);
        union { unsigned int u[4]; bf16x8 v; } pk;
        pk.u[0] = w00; pk.u[1] = w01; pk.u[2] = w10; pk.u[3] = w11;
        ot[qf][0] = __builtin_amdgcn_mfma_f32_16x16x32_bf16(vb[0][0], pk.v,
                                                            ot[qf][0], 0, 0, 0);
        ot[qf][1] = __builtin_amdgcn_mfma_f32_16x16x32_bf16(vb[1][0], pk.v,
                                                            ot[qf][1], 0, 0, 0);
      }
      {
        float pa0 = EXP2(sC[0]), pa1 = EXP2(sC[1]);
        float pa2 = EXP2(sC[2]), pa3 = EXP2(sC[3]);
        float pb0 = EXP2(sD[0]), pb1 = EXP2(sD[1]);
        float pb2 = EXP2(sD[2]), pb3 = EXP2(sD[3]);
        l[qf] += ((pa0 + pa1) + (pa2 + pa3)) + ((pb0 + pb1) + (pb2 + pb3));
        unsigned int w00 = cvtpk_bf16(pa0, pa1), w01 = cvtpk_bf16(pa2, pa3);
        unsigned int w10 = cvtpk_bf16(pb0, pb1), w11 = cvtpk_bf16(pb2, pb3);
        plswap32(w00, w10); plswap16(w00, w10);
        plswap32(w01, w11); plswap16(w01, w11);
        union { unsigned int u[4]; bf16x8 v; } pk;
        pk.u[0] = w00; pk.u[1] = w01; pk.u[2] = w10; pk.u[3] = w11;
        ot[qf][0] = __builtin_amdgcn_mfma_f32_16x16x32_bf16(vb[0][1], pk.v,
                                                            ot[qf][0], 0, 0, 0);
        ot[qf][1] = __builtin_amdgcn_mfma_f32_16x16x32_bf16(vb[1][1], pk.v,
                                                            ot[qf][1], 0, 0, 0);
      }
    }
  }

#pragma unroll
  for (int qf = 0; qf < 4; ++qf) {
    l[qf] += __shfl_xor(l[qf], 16);
    l[qf] += __shfl_xor(l[qf], 32);
  }
#pragma unroll
  for (int qf = 0; qf < 4; ++qf) {
    float rl = 1.0f / l[qf];
#pragma unroll
    for (int hf = 0; hf < 2; ++hf) {
      ushort4 pk;
      pk.x = f2bf(ot[qf][hf][0] * rl);
      pk.y = f2bf(ot[qf][hf][1] * rl);
      pk.z = f2bf(ot[qf][hf][2] * rl);
      pk.w = f2bf(ot[qf][hf][3] * rl);
      *(ushort4*)(obf + (tok0 + wv * 64 + qf * 16 + c) * 128 + hh * 32 +
                  hf * 16 + g * 4) = pk;
    }
  }
}

// ---------------------------------------------------------------------------
__global__ __launch_bounds__(64) void avg_entropy_kernel(
    const float* __restrict__ ent, float* __restrict__ out) {
  int s = blockIdx.x, lane = threadIdx.x;
  float a = 0.f;
  for (int b = lane; b < 256; b += 64) a += ent[(size_t)b * 512 + s];
#pragma unroll
  for (int off = 32; off; off >>= 1) a += __shfl_xor(a, off);
  if (lane == 0) out[s] = a * 0.00390625f;
}

__global__ __launch_bounds__(512) void seg_kernel(float* out) {
  __shared__ int cs[512];
  int i = threadIdx.x;
  float e = out[i];
  cs[i] = (i >= 1 && e > 4.0f) ? 1 : 0;
  __syncthreads();
  for (int off = 1; off < 512; off <<= 1) {
    int v = (i >= off) ? cs[i - off] : 0;
    __syncthreads();
    cs[i] += v;
    __syncthreads();
  }
  out[512 + i] = (float)cs[i];
}

// ---------------------------------------------------------------------------
extern "C" void kernel_launch(void* const* d_in, const int* in_sizes, int n_in,
                              void* d_out, int out_size, void* d_ws,
                              size_t ws_size, hipStream_t stream) {
  (void)in_sizes; (void)n_in; (void)out_size; (void)ws_size;
  const int*   input_bytes = (const int*)d_in[0];
  const float* emb    = (const float*)d_in[1];
  const float* pos    = (const float*)d_in[2];
  const float* ln_g   = (const float*)d_in[3];
  const float* ln_b   = (const float*)d_in[4];
  const float* attn_w = (const float*)d_in[5];
  const float* attn_b = (const float*)d_in[6];
  const float* out_w  = (const float*)d_in[7];
  const float* out_b  = (const float*)d_in[8];
  const float* ff1_w  = (const float*)d_in[9];
  const float* ff1_b  = (const float*)d_in[10];
  const float* ff2_w  = (const float*)d_in[11];
  const float* ff2_b  = (const float*)d_in[12];
  const float* n1_g   = (const float*)d_in[13];
  const float* n1_b   = (const float*)d_in[14];
  const float* n2_g   = (const float*)d_in[15];
  const float* n2_b   = (const float*)d_in[16];
  const float* proj_w = (const float*)d_in[17];
  const float* proj_b = (const float*)d_in[18];

  char* ws = (char*)d_ws;
  unsigned short* hbf  = (unsigned short*)(ws);                // 32 MB
  unsigned short* obf  = (unsigned short*)(ws + 33554432);     // 32 MB
  unsigned short* qkvc = (unsigned short*)(ws + 67108864);     // 96 MB
  unsigned short* wbf  = (unsigned short*)(ws + 167772160);    // ~0.85 MB
  float*          absb = (float*)(ws + 168624128);             // 3 KB
  float*          entb = (float*)(ws + 168628224);             // 0.5 MB

  unsigned short* attnw_bf = wbf;
  unsigned short* outw_bf  = wbf + 98304;
  unsigned short* w1p      = wbf + 131072;
  unsigned short* w2p      = wbf + 262144;
  unsigned short* projw_bf = wbf + 393216;

  conv_attn_w<<<384, 256, 0, stream>>>(attn_w, attnw_bf);
  conv_attn_b<<<3, 256, 0, stream>>>(attn_b, absb);
  f32_to_bf16<<<128, 256, 0, stream>>>(out_w, outw_bf, 32768);
  conv_perm<<<512, 256, 0, stream>>>(ff1_w, w1p, 128, 131072);
  conv_perm<<<512, 256, 0, stream>>>(ff2_w, w2p, 512, 131072);
  f32_to_bf16<<<128, 256, 0, stream>>>(proj_w, projw_bf, 32768);

  embed_ln<<<32768, 256, 0, stream>>>(input_bytes, emb, pos, ln_g, ln_b, hbf);

  for (int l = 0; l < 2; ++l) {
    // QKV GEMM (bf16 out, Q pre-scaled) full M, then attention full batch
    gemm_bf16<0, 1><<<dim3(3, 1024), 256, 0, stream>>>(
        hbf, attnw_bf + l * 49152, absb + l * 384, qkvc, 131072, 384, 128);
    attn_mfma<<<1024, 512, 0, stream>>>(qkvc, obf);
    // fused out-proj + residual + LN1 (in place on hbf)
    gemm_ln_res<<<1024, 256, 0, stream>>>(
        obf, outw_bf + l * 16384, out_b + l * 128, hbf,
        n1_g + l * 128, n1_b + l * 128, hbf, 131072, 128);
    // fused FFN + residual + LN2 (in place on hbf)
    ffn_fused<<<1024, 512, 0, stream>>>(
        hbf, w1p + l * 65536, ff1_b + l * 512, w2p + l * 65536,
        ff2_b + l * 128, n2_g + l * 128, n2_b + l * 128, hbf);
  }

  // fused vocab projection + entropy
  gemm_entropy<<<1024, 512, 0, stream>>>(hbf, projw_bf, proj_b, entb, 128);
  avg_entropy_kernel<<<512, 64, 0, stream>>>(entb, (float*)d_out);
  seg_kernel<<<1, 512, 0, stream>>>((float*)d_out);
}

// Round 7
// 500.042 us; speedup vs baseline: 1.8125x; 1.1000x over previous
//
#include <hip/hip_runtime.h>

// ---------------------------------------------------------------------------
// EntropyCalculator: 2-layer post-norm transformer encoder + entropy head.
// B=256 S=512 D=128 H=4 HD=32 FF=512 V=256
// Register-transposed barrier-free oproj/FFN/entropy; MFMA flash attention.
// ---------------------------------------------------------------------------

#define AS1 __attribute__((address_space(1)))
#define AS3 __attribute__((address_space(3)))

typedef __bf16 bf16x8 __attribute__((ext_vector_type(8)));
typedef float  f32x4  __attribute__((ext_vector_type(4)));

__device__ __forceinline__ unsigned short f2bf(float f) {
  union { float f; unsigned int u; } c; c.f = f;
  unsigned int u = c.u;
  u += 0x7FFFu + ((u >> 16) & 1u);   // round-to-nearest-even
  return (unsigned short)(u >> 16);
}
__device__ __forceinline__ float bf2f(unsigned short u) {
  union { unsigned int u; float f; } c; c.u = ((unsigned int)u) << 16;
  return c.f;
}

__device__ __forceinline__ float EXP2(float x) {
#if __has_builtin(__builtin_amdgcn_exp2f)
  return __builtin_amdgcn_exp2f(x);
#else
  return exp2f(x);
#endif
}

__device__ __forceinline__ void async_copy16(const void* g, void* l) {
  __builtin_amdgcn_global_load_lds((AS1 void*)(void*)g, (AS3 void*)l, 16, 0, 0);
}

__device__ __forceinline__ unsigned int cvtpk_bf16(float lo, float hi) {
  unsigned int r;
  asm("v_cvt_pk_bf16_f32 %0, %1, %2" : "=v"(r) : "v"(lo), "v"(hi));
  return r;
}
__device__ __forceinline__ void plswap32(unsigned int& a, unsigned int& b) {
  asm("v_permlane32_swap_b32 %0, %1" : "+v"(a), "+v"(b));
}
__device__ __forceinline__ void plswap16(unsigned int& a, unsigned int& b) {
  asm("v_permlane16_swap_b32 %0, %1" : "+v"(a), "+v"(b));
}

#define MFMA __builtin_amdgcn_mfma_f32_16x16x32_bf16

// ---------------------------------------------------------------------------
// weight conversions
// ---------------------------------------------------------------------------
// [N][K] f32 -> bf16 A-operand fragment lane order:
// frag (nb=row>>4, kb=k>>5) is 1KB contiguous; within frag, lane l=(g*16+c)
// holds row nb*16+c, k kb*32+g*8..+7 at halfword offset l*8.
__global__ void conv_permA(const float* __restrict__ src,
                           unsigned short* __restrict__ dst, int K, int n) {
  int i = blockIdx.x * 256 + threadIdx.x;
  if (i >= n) return;
  int row = i / K, k = i - row * K;
  int frag = (row >> 4) * (K >> 5) + (k >> 5);
  int d = frag * 512 + ((k >> 3) & 3) * 128 + (row & 15) * 8 + (k & 7);
  dst[d] = f2bf(src[i]);
}

// attn_w with Q rows pre-scaled by (1/sqrt(HD))*log2(e)
#define QSCALE 0.2550602989892646f
__global__ void conv_attn_w(const float* __restrict__ src,
                            unsigned short* __restrict__ dst) {
  int i = blockIdx.x * 256 + threadIdx.x;  // 98304
  int r = (i >> 7) % 384;
  float v = src[i];
  if (r < 128) v *= QSCALE;
  dst[i] = f2bf(v);
}
__global__ void conv_attn_b(const float* __restrict__ src,
                            float* __restrict__ dst) {
  int i = blockIdx.x * 256 + threadIdx.x;  // 768
  if (i < 768) {
    float v = src[i];
    if ((i % 384) < 128) v *= QSCALE;
    dst[i] = v;
  }
}

// ---------------------------------------------------------------------------
// Embedding + LayerNorm -> bf16 residual stream.  One wave per token.
// ---------------------------------------------------------------------------
__global__ __launch_bounds__(256) void embed_ln(
    const int* __restrict__ bytes, const float* __restrict__ emb,
    const float* __restrict__ pos, const float* __restrict__ g,
    const float* __restrict__ bta, unsigned short* __restrict__ hbf) {
  int wv = threadIdx.x >> 6, lane = threadIdx.x & 63;
  int tok = blockIdx.x * 4 + wv;
  int s = tok & 511;
  int bidx = bytes[tok];
  const float* e = emb + (size_t)bidx * 128;
  const float* p = pos + (size_t)s * 128;
  float x0 = e[lane] + p[lane];
  float x1 = e[lane + 64] + p[lane + 64];
  float sum = x0 + x1, ssq = x0 * x0 + x1 * x1;
#pragma unroll
  for (int off = 32; off; off >>= 1) {
    sum += __shfl_xor(sum, off);
    ssq += __shfl_xor(ssq, off);
  }
  float mean = sum * 0.0078125f;
  float var = ssq * 0.0078125f - mean * mean;
  float rs = rsqrtf(var + 1e-5f);
  float y0 = (x0 - mean) * rs * g[lane] + bta[lane];
  float y1 = (x1 - mean) * rs * g[lane + 64] + bta[lane + 64];
  size_t o = (size_t)tok * 128;
  hbf[o + lane] = f2bf(y0); hbf[o + lane + 64] = f2bf(y1);
}

// ---------------------------------------------------------------------------
// bf16 MFMA GEMM (QKV only):  C[M,N] = A[M,K] @ W[N,K]^T + bias, bf16 out.
// 128x128 tile, BK=64, 4 waves.
// ---------------------------------------------------------------------------
__global__ __launch_bounds__(256) void gemm_qkv(
    const unsigned short* __restrict__ A, const unsigned short* __restrict__ W,
    const float* __restrict__ bias, unsigned short* __restrict__ Cout,
    int M, int N, int K) {
  __shared__ __bf16 As[128 * 64];
  __shared__ __bf16 Ws[128 * 64];
  const int t = threadIdx.x;
  const int lane = t & 63, w = t >> 6;
  const int m0 = blockIdx.y * 128, n0 = blockIdx.x * 128;
  const int wm = (w >> 1) * 64, wn = (w & 1) * 64;
  f32x4 acc[4][4] = {};
  const int srow = w * 32 + (lane >> 3);
  const int scol = (lane & 7) * 8;

  for (int k0 = 0; k0 < K; k0 += 64) {
#pragma unroll
    for (int j = 0; j < 4; ++j) {
      int r = srow + j * 8;
      int ldsrow = w * 32 + j * 8;
      async_copy16(A + (size_t)(m0 + r) * K + k0 + scol, &As[ldsrow * 64]);
      async_copy16(W + (size_t)(n0 + r) * K + k0 + scol, &Ws[ldsrow * 64]);
    }
    __syncthreads();
#pragma unroll
    for (int kk = 0; kk < 2; ++kk) {
      bf16x8 af[4], bfr[4];
#pragma unroll
      for (int f = 0; f < 4; ++f) {
        af[f]  = *(const bf16x8*)&As[(wm + f * 16 + (lane & 15)) * 64 + kk * 32 + (lane >> 4) * 8];
        bfr[f] = *(const bf16x8*)&Ws[(wn + f * 16 + (lane & 15)) * 64 + kk * 32 + (lane >> 4) * 8];
      }
#pragma unroll
      for (int fi = 0; fi < 4; ++fi)
#pragma unroll
        for (int fj = 0; fj < 4; ++fj)
          acc[fi][fj] = MFMA(af[fi], bfr[fj], acc[fi][fj], 0, 0, 0);
    }
    __syncthreads();
  }

#pragma unroll
  for (int fj = 0; fj < 4; ++fj) {
    int col = n0 + wn + fj * 16 + (lane & 15);
    float bv = bias[col];
#pragma unroll
    for (int fi = 0; fi < 4; ++fi) {
#pragma unroll
      for (int r2 = 0; r2 < 4; ++r2) {
        int row = m0 + wm + fi * 16 + (lane >> 4) * 4 + r2;
        Cout[(size_t)row * N + col] = f2bf(acc[fi][fj][r2] + bv);
      }
    }
  }
}

// ---------------------------------------------------------------------------
// Fused out-proj + residual + LayerNorm, register-transposed, no LDS/barrier.
// 256 thr = 4 waves; wave owns 32 tokens (2 frags), full d=128 (8 frags).
// O^T[d][tok] = mfma(Wfrag_A[d16 x k32], tokfrag_B[tok16 x k32]).
// ---------------------------------------------------------------------------
__global__ __launch_bounds__(256) void oproj_ln(
    const unsigned short* __restrict__ A, const unsigned short* __restrict__ Wp,
    const float* __restrict__ bias, unsigned short* __restrict__ h,
    const float* __restrict__ gamma, const float* __restrict__ beta) {
  const int lane = threadIdx.x & 63, w = threadIdx.x >> 6;
  const int c = lane & 15, g = lane >> 4;
  const size_t tok0 = (size_t)blockIdx.x * 128 + w * 32;

  bf16x8 at[2][4];
#pragma unroll
  for (int tf = 0; tf < 2; ++tf)
#pragma unroll
    for (int kk = 0; kk < 4; ++kk)
      at[tf][kk] =
          *(const bf16x8*)(A + (tok0 + tf * 16 + c) * 128 + kk * 32 + g * 8);

  f32x4 acc[8][2] = {};
#pragma unroll
  for (int db = 0; db < 8; ++db)
#pragma unroll
    for (int kk = 0; kk < 4; ++kk) {
      bf16x8 wf = *(const bf16x8*)(Wp + (db * 4 + kk) * 512 + lane * 8);
      acc[db][0] = MFMA(wf, at[0][kk], acc[db][0], 0, 0, 0);
      acc[db][1] = MFMA(wf, at[1][kk], acc[db][1], 0, 0, 0);
    }

#pragma unroll
  for (int tf = 0; tf < 2; ++tf) {
    unsigned short* hrow = h + (tok0 + tf * 16 + c) * 128;
    float x[8][4];
    float s_ = 0.f, q_ = 0.f;
#pragma unroll
    for (int db = 0; db < 8; ++db) {
      float4 bv = *(const float4*)(bias + db * 16 + g * 4);
      ushort4 rv = *(const ushort4*)(hrow + db * 16 + g * 4);
      x[db][0] = acc[db][tf][0] + bv.x + bf2f(rv.x);
      x[db][1] = acc[db][tf][1] + bv.y + bf2f(rv.y);
      x[db][2] = acc[db][tf][2] + bv.z + bf2f(rv.z);
      x[db][3] = acc[db][tf][3] + bv.w + bf2f(rv.w);
#pragma unroll
      for (int r = 0; r < 4; ++r) { s_ += x[db][r]; q_ += x[db][r] * x[db][r]; }
    }
    s_ += __shfl_xor(s_, 16); s_ += __shfl_xor(s_, 32);
    q_ += __shfl_xor(q_, 16); q_ += __shfl_xor(q_, 32);
    float mean = s_ * 0.0078125f;
    float var = q_ * 0.0078125f - mean * mean;
    float rs = rsqrtf(var + 1e-5f);
#pragma unroll
    for (int db = 0; db < 8; ++db) {
      float4 gv = *(const float4*)(gamma + db * 16 + g * 4);
      float4 bb = *(const float4*)(beta + db * 16 + g * 4);
      ushort4 o;
      o.x = f2bf((x[db][0] - mean) * rs * gv.x + bb.x);
      o.y = f2bf((x[db][1] - mean) * rs * gv.y + bb.y);
      o.z = f2bf((x[db][2] - mean) * rs * gv.z + bb.z);
      o.w = f2bf((x[db][3] - mean) * rs * gv.w + bb.w);
      *(ushort4*)(hrow + db * 16 + g * 4) = o;
    }
  }
}

// ---------------------------------------------------------------------------
// Fused FFN, register-transposed, G never leaves registers, no LDS/barriers.
// G^T = mfma(W1frag, tokfrag); relu+bias; cvt_pk+permlane -> gemm2 B-operand;
// O^T += mfma(W2frag, Gpacked).  Epilogue: residual + LN (in place on h).
// ---------------------------------------------------------------------------
__global__ __launch_bounds__(256) void ffn_reg(
    unsigned short* __restrict__ h, const unsigned short* __restrict__ W1p,
    const float* __restrict__ b1, const unsigned short* __restrict__ W2p,
    const float* __restrict__ b2, const float* __restrict__ gamma,
    const float* __restrict__ beta) {
  const int lane = threadIdx.x & 63, w = threadIdx.x >> 6;
  const int c = lane & 15, g = lane >> 4;
  const size_t tok0 = (size_t)blockIdx.x * 128 + w * 32;

  bf16x8 at[2][4];
#pragma unroll
  for (int tf = 0; tf < 2; ++tf)
#pragma unroll
    for (int kk = 0; kk < 4; ++kk)
      at[tf][kk] =
          *(const bf16x8*)(h + (tok0 + tf * 16 + c) * 128 + kk * 32 + g * 8);

  f32x4 acc[8][2] = {};
  for (int s = 0; s < 16; ++s) {          // 16 slices of 32 ff
    f32x4 d1[2][2] = {};                  // [ffhalf][tf]
#pragma unroll
    for (int kk = 0; kk < 4; ++kk) {
      bf16x8 wa = *(const bf16x8*)(W1p + ((2 * s) * 4 + kk) * 512 + lane * 8);
      bf16x8 wb = *(const bf16x8*)(W1p + ((2 * s + 1) * 4 + kk) * 512 + lane * 8);
      d1[0][0] = MFMA(wa, at[0][kk], d1[0][0], 0, 0, 0);
      d1[0][1] = MFMA(wa, at[1][kk], d1[0][1], 0, 0, 0);
      d1[1][0] = MFMA(wb, at[0][kk], d1[1][0], 0, 0, 0);
      d1[1][1] = MFMA(wb, at[1][kk], d1[1][1], 0, 0, 0);
    }
    float4 bva = *(const float4*)(b1 + s * 32 + g * 4);
    float4 bvb = *(const float4*)(b1 + s * 32 + 16 + g * 4);
    bf16x8 gp[2];
#pragma unroll
    for (int tf = 0; tf < 2; ++tf) {
      float pa0 = fmaxf(d1[0][tf][0] + bva.x, 0.f);
      float pa1 = fmaxf(d1[0][tf][1] + bva.y, 0.f);
      float pa2 = fmaxf(d1[0][tf][2] + bva.z, 0.f);
      float pa3 = fmaxf(d1[0][tf][3] + bva.w, 0.f);
      float pb0 = fmaxf(d1[1][tf][0] + bvb.x, 0.f);
      float pb1 = fmaxf(d1[1][tf][1] + bvb.y, 0.f);
      float pb2 = fmaxf(d1[1][tf][2] + bvb.z, 0.f);
      float pb3 = fmaxf(d1[1][tf][3] + bvb.w, 0.f);
      unsigned int w00 = cvtpk_bf16(pa0, pa1), w01 = cvtpk_bf16(pa2, pa3);
      unsigned int w10 = cvtpk_bf16(pb0, pb1), w11 = cvtpk_bf16(pb2, pb3);
      plswap32(w00, w10); plswap16(w00, w10);
      plswap32(w01, w11); plswap16(w01, w11);
      union { unsigned int u[4]; bf16x8 v; } pk;
      pk.u[0] = w00; pk.u[1] = w01; pk.u[2] = w10; pk.u[3] = w11;
      gp[tf] = pk.v;
    }
#pragma unroll
    for (int db = 0; db < 8; ++db) {
      bf16x8 w2 = *(const bf16x8*)(W2p + (db * 16 + s) * 512 + lane * 8);
      acc[db][0] = MFMA(w2, gp[0], acc[db][0], 0, 0, 0);
      acc[db][1] = MFMA(w2, gp[1], acc[db][1], 0, 0, 0);
    }
  }

#pragma unroll
  for (int tf = 0; tf < 2; ++tf) {
    unsigned short* hrow = h + (tok0 + tf * 16 + c) * 128;
    float x[8][4];
    float s_ = 0.f, q_ = 0.f;
#pragma unroll
    for (int db = 0; db < 8; ++db) {
      float4 bv = *(const float4*)(b2 + db * 16 + g * 4);
      ushort4 rv = *(const ushort4*)(hrow + db * 16 + g * 4);
      x[db][0] = acc[db][tf][0] + bv.x + bf2f(rv.x);
      x[db][1] = acc[db][tf][1] + bv.y + bf2f(rv.y);
      x[db][2] = acc[db][tf][2] + bv.z + bf2f(rv.z);
      x[db][3] = acc[db][tf][3] + bv.w + bf2f(rv.w);
#pragma unroll
      for (int r = 0; r < 4; ++r) { s_ += x[db][r]; q_ += x[db][r] * x[db][r]; }
    }
    s_ += __shfl_xor(s_, 16); s_ += __shfl_xor(s_, 32);
    q_ += __shfl_xor(q_, 16); q_ += __shfl_xor(q_, 32);
    float mean = s_ * 0.0078125f;
    float var = q_ * 0.0078125f - mean * mean;
    float rs = rsqrtf(var + 1e-5f);
#pragma unroll
    for (int db = 0; db < 8; ++db) {
      float4 gv = *(const float4*)(gamma + db * 16 + g * 4);
      float4 bb = *(const float4*)(beta + db * 16 + g * 4);
      ushort4 o;
      o.x = f2bf((x[db][0] - mean) * rs * gv.x + bb.x);
      o.y = f2bf((x[db][1] - mean) * rs * gv.y + bb.y);
      o.z = f2bf((x[db][2] - mean) * rs * gv.z + bb.z);
      o.w = f2bf((x[db][3] - mean) * rs * gv.w + bb.w);
      *(ushort4*)(hrow + db * 16 + g * 4) = o;
    }
  }
}

// ---------------------------------------------------------------------------
// Fused vocab projection + entropy, register-transposed, no LDS/barriers.
// E^T[v][tok] = mfma(ProjWfrag, tokfrag); entropy per token = per lane column.
// ---------------------------------------------------------------------------
__global__ __launch_bounds__(256) void vocab_entropy(
    const unsigned short* __restrict__ h, const unsigned short* __restrict__ Wp,
    const float* __restrict__ bias, float* __restrict__ ent) {
  const int lane = threadIdx.x & 63, w = threadIdx.x >> 6;
  const int c = lane & 15, g = lane >> 4;
  const size_t tok0 = (size_t)blockIdx.x * 128 + w * 32;

  bf16x8 at[2][4];
#pragma unroll
  for (int tf = 0; tf < 2; ++tf)
#pragma unroll
    for (int kk = 0; kk < 4; ++kk)
      at[tf][kk] =
          *(const bf16x8*)(h + (tok0 + tf * 16 + c) * 128 + kk * 32 + g * 8);

  f32x4 acc[16][2] = {};
#pragma unroll
  for (int vb = 0; vb < 16; ++vb)
#pragma unroll
    for (int kk = 0; kk < 4; ++kk) {
      bf16x8 wf = *(const bf16x8*)(Wp + (vb * 4 + kk) * 512 + lane * 8);
      acc[vb][0] = MFMA(wf, at[0][kk], acc[vb][0], 0, 0, 0);
      acc[vb][1] = MFMA(wf, at[1][kk], acc[vb][1], 0, 0, 0);
    }

  const float L2E = 1.4426950408889634f;
#pragma unroll
  for (int tf = 0; tf < 2; ++tf) {
    float m_ = -1e30f;
#pragma unroll
    for (int vb = 0; vb < 16; ++vb) {
      float4 bv = *(const float4*)(bias + vb * 16 + g * 4);
      acc[vb][tf][0] += bv.x; acc[vb][tf][1] += bv.y;
      acc[vb][tf][2] += bv.z; acc[vb][tf][3] += bv.w;
      m_ = fmaxf(m_, fmaxf(fmaxf(acc[vb][tf][0], acc[vb][tf][1]),
                           fmaxf(acc[vb][tf][2], acc[vb][tf][3])));
    }
    m_ = fmaxf(m_, __shfl_xor(m_, 16));
    m_ = fmaxf(m_, __shfl_xor(m_, 32));
    float z_ = 0.f, sx_ = 0.f;
#pragma unroll
    for (int vb = 0; vb < 16; ++vb)
#pragma unroll
      for (int r = 0; r < 4; ++r) {
        float xx = acc[vb][tf][r];
        float e = EXP2((xx - m_) * L2E);
        z_ += e; sx_ += e * xx;
      }
    z_ += __shfl_xor(z_, 16);  z_ += __shfl_xor(z_, 32);
    sx_ += __shfl_xor(sx_, 16); sx_ += __shfl_xor(sx_, 32);
    if (g == 0) ent[tok0 + tf * 16 + c] = m_ + logf(z_) - sx_ / z_;
  }
}

// ---------------------------------------------------------------------------
// MFMA flash attention, register-resident P.  Q pre-scaled by scale*log2e.
// One block (512 thr = 8 waves) per (batch, head).
// ---------------------------------------------------------------------------
__global__ __launch_bounds__(512, 4) void attn_mfma(
    const unsigned short* __restrict__ qkv, unsigned short* __restrict__ obf) {
  __shared__ __bf16 Ks[512 * 40];
  __shared__ __bf16 Vt[32 * 520];

  const int hh = blockIdx.x & 3, bl = blockIdx.x >> 2;
  const int t = threadIdx.x;
  const int lane = t & 63, wv = t >> 6;
  const int c = lane & 15, g = lane >> 4;
  const size_t tok0 = (size_t)bl * 512;

  {
    const unsigned short* kr = qkv + (tok0 + t) * 384 + 128 + hh * 32;
    bf16x8 k0 = *(const bf16x8*)(kr);
    bf16x8 k1 = *(const bf16x8*)(kr + 8);
    bf16x8 k2 = *(const bf16x8*)(kr + 16);
    bf16x8 k3 = *(const bf16x8*)(kr + 24);
    __bf16* kd = Ks + t * 40;
    *(bf16x8*)(kd + 0) = k0;  *(bf16x8*)(kd + 8) = k1;
    *(bf16x8*)(kd + 16) = k2; *(bf16x8*)(kd + 24) = k3;
    const unsigned short* vr = kr + 128;
    bf16x8 v0 = *(const bf16x8*)(vr);
    bf16x8 v1 = *(const bf16x8*)(vr + 8);
    bf16x8 v2 = *(const bf16x8*)(vr + 16);
    bf16x8 v3 = *(const bf16x8*)(vr + 24);
#pragma unroll
    for (int i = 0; i < 8; ++i) {
      Vt[(i)      * 520 + t] = v0[i];
      Vt[(i + 8)  * 520 + t] = v1[i];
      Vt[(i + 16) * 520 + t] = v2[i];
      Vt[(i + 24) * 520 + t] = v3[i];
    }
  }

  bf16x8 qb[4];
  {
    const unsigned short* qp = qkv + (tok0 + wv * 64) * 384 + hh * 32;
#pragma unroll
    for (int qf = 0; qf < 4; ++qf)
      qb[qf] = *(const bf16x8*)(qp + (size_t)(qf * 16 + c) * 384 + g * 8);
  }
  __syncthreads();

  f32x4 ot[4][2] = {};
  float l[4] = {0.f, 0.f, 0.f, 0.f};
  const f32x4 zz = {0.f, 0.f, 0.f, 0.f};

  for (int kt = 0; kt < 8; ++kt) {
    bf16x8 ka[4];
#pragma unroll
    for (int kf = 0; kf < 4; ++kf)
      ka[kf] = *(const bf16x8*)&Ks[(kt * 64 + kf * 16 + c) * 40 + g * 8];
    bf16x8 vb[2][2];
#pragma unroll
    for (int hf = 0; hf < 2; ++hf)
#pragma unroll
      for (int ksl = 0; ksl < 2; ++ksl)
        vb[hf][ksl] =
            *(const bf16x8*)&Vt[(hf * 16 + c) * 520 + kt * 64 + ksl * 32 + g * 8];

#pragma unroll
    for (int qf = 0; qf < 4; ++qf) {
      f32x4 sA = MFMA(ka[0], qb[qf], zz, 0, 0, 0);
      f32x4 sB = MFMA(ka[1], qb[qf], zz, 0, 0, 0);
      f32x4 sC = MFMA(ka[2], qb[qf], zz, 0, 0, 0);
      f32x4 sD = MFMA(ka[3], qb[qf], zz, 0, 0, 0);

      {
        float pa0 = EXP2(sA[0]), pa1 = EXP2(sA[1]);
        float pa2 = EXP2(sA[2]), pa3 = EXP2(sA[3]);
        float pb0 = EXP2(sB[0]), pb1 = EXP2(sB[1]);
        float pb2 = EXP2(sB[2]), pb3 = EXP2(sB[3]);
        l[qf] += ((pa0 + pa1) + (pa2 + pa3)) + ((pb0 + pb1) + (pb2 + pb3));
        unsigned int w00 = cvtpk_bf16(pa0, pa1), w01 = cvtpk_bf16(pa2, pa3);
        unsigned int w10 = cvtpk_bf16(pb0, pb1), w11 = cvtpk_bf16(pb2, pb3);
        plswap32(w00, w10); plswap16(w00, w10);
        plswap32(w01, w11); plswap16(w01, w11);
        union { unsigned int u[4]; bf16x8 v; } pk;
        pk.u[0] = w00; pk.u[1] = w01; pk.u[2] = w10; pk.u[3] = w11;
        ot[qf][0] = MFMA(vb[0][0], pk.v, ot[qf][0], 0, 0, 0);
        ot[qf][1] = MFMA(vb[1][0], pk.v, ot[qf][1], 0, 0, 0);
      }
      {
        float pa0 = EXP2(sC[0]), pa1 = EXP2(sC[1]);
        float pa2 = EXP2(sC[2]), pa3 = EXP2(sC[3]);
        float pb0 = EXP2(sD[0]), pb1 = EXP2(sD[1]);
        float pb2 = EXP2(sD[2]), pb3 = EXP2(sD[3]);
        l[qf] += ((pa0 + pa1) + (pa2 + pa3)) + ((pb0 + pb1) + (pb2 + pb3));
        unsigned int w00 = cvtpk_bf16(pa0, pa1), w01 = cvtpk_bf16(pa2, pa3);
        unsigned int w10 = cvtpk_bf16(pb0, pb1), w11 = cvtpk_bf16(pb2, pb3);
        plswap32(w00, w10); plswap16(w00, w10);
        plswap32(w01, w11); plswap16(w01, w11);
        union { unsigned int u[4]; bf16x8 v; } pk;
        pk.u[0] = w00; pk.u[1] = w01; pk.u[2] = w10; pk.u[3] = w11;
        ot[qf][0] = MFMA(vb[0][1], pk.v, ot[qf][0], 0, 0, 0);
        ot[qf][1] = MFMA(vb[1][1], pk.v, ot[qf][1], 0, 0, 0);
      }
    }
  }

#pragma unroll
  for (int qf = 0; qf < 4; ++qf) {
    l[qf] += __shfl_xor(l[qf], 16);
    l[qf] += __shfl_xor(l[qf], 32);
  }
#pragma unroll
  for (int qf = 0; qf < 4; ++qf) {
    float rl = 1.0f / l[qf];
#pragma unroll
    for (int hf = 0; hf < 2; ++hf) {
      ushort4 pk;
      pk.x = f2bf(ot[qf][hf][0] * rl);
      pk.y = f2bf(ot[qf][hf][1] * rl);
      pk.z = f2bf(ot[qf][hf][2] * rl);
      pk.w = f2bf(ot[qf][hf][3] * rl);
      *(ushort4*)(obf + (tok0 + wv * 64 + qf * 16 + c) * 128 + hh * 32 +
                  hf * 16 + g * 4) = pk;
    }
  }
}

// ---------------------------------------------------------------------------
__global__ __launch_bounds__(64) void avg_entropy_kernel(
    const float* __restrict__ ent, float* __restrict__ out) {
  int s = blockIdx.x, lane = threadIdx.x;
  float a = 0.f;
  for (int b = lane; b < 256; b += 64) a += ent[(size_t)b * 512 + s];
#pragma unroll
  for (int off = 32; off; off >>= 1) a += __shfl_xor(a, off);
  if (lane == 0) out[s] = a * 0.00390625f;
}

__global__ __launch_bounds__(512) void seg_kernel(float* out) {
  __shared__ int cs[512];
  int i = threadIdx.x;
  float e = out[i];
  cs[i] = (i >= 1 && e > 4.0f) ? 1 : 0;
  __syncthreads();
  for (int off = 1; off < 512; off <<= 1) {
    int v = (i >= off) ? cs[i - off] : 0;
    __syncthreads();
    cs[i] += v;
    __syncthreads();
  }
  out[512 + i] = (float)cs[i];
}

// ---------------------------------------------------------------------------
extern "C" void kernel_launch(void* const* d_in, const int* in_sizes, int n_in,
                              void* d_out, int out_size, void* d_ws,
                              size_t ws_size, hipStream_t stream) {
  (void)in_sizes; (void)n_in; (void)out_size; (void)ws_size;
  const int*   input_bytes = (const int*)d_in[0];
  const float* emb    = (const float*)d_in[1];
  const float* pos    = (const float*)d_in[2];
  const float* ln_g   = (const float*)d_in[3];
  const float* ln_b   = (const float*)d_in[4];
  const float* attn_w = (const float*)d_in[5];
  const float* attn_b = (const float*)d_in[6];
  const float* out_w  = (const float*)d_in[7];
  const float* out_b  = (const float*)d_in[8];
  const float* ff1_w  = (const float*)d_in[9];
  const float* ff1_b  = (const float*)d_in[10];
  const float* ff2_w  = (const float*)d_in[11];
  const float* ff2_b  = (const float*)d_in[12];
  const float* n1_g   = (const float*)d_in[13];
  const float* n1_b   = (const float*)d_in[14];
  const float* n2_g   = (const float*)d_in[15];
  const float* n2_b   = (const float*)d_in[16];
  const float* proj_w = (const float*)d_in[17];
  const float* proj_b = (const float*)d_in[18];

  char* ws = (char*)d_ws;
  unsigned short* hbf  = (unsigned short*)(ws);                // 32 MB
  unsigned short* obf  = (unsigned short*)(ws + 33554432);     // 32 MB
  unsigned short* qkvc = (unsigned short*)(ws + 67108864);     // 96 MB
  unsigned short* wbf  = (unsigned short*)(ws + 167772160);    // ~0.85 MB
  float*          absb = (float*)(ws + 168624128);             // 3 KB
  float*          entb = (float*)(ws + 168628224);             // 0.5 MB

  unsigned short* attnw_bf = wbf;
  unsigned short* outwA    = wbf + 98304;
  unsigned short* w1A      = wbf + 131072;
  unsigned short* w2A      = wbf + 262144;
  unsigned short* projA    = wbf + 393216;

  conv_attn_w<<<384, 256, 0, stream>>>(attn_w, attnw_bf);
  conv_attn_b<<<3, 256, 0, stream>>>(attn_b, absb);
  for (int l = 0; l < 2; ++l) {
    conv_permA<<<64, 256, 0, stream>>>(out_w + l * 16384, outwA + l * 16384,
                                       128, 16384);
    conv_permA<<<256, 256, 0, stream>>>(ff1_w + l * 65536, w1A + l * 65536,
                                        128, 65536);
    conv_permA<<<256, 256, 0, stream>>>(ff2_w + l * 65536, w2A + l * 65536,
                                        512, 65536);
  }
  conv_permA<<<128, 256, 0, stream>>>(proj_w, projA, 128, 32768);

  embed_ln<<<32768, 256, 0, stream>>>(input_bytes, emb, pos, ln_g, ln_b, hbf);

  for (int l = 0; l < 2; ++l) {
    gemm_qkv<<<dim3(3, 1024), 256, 0, stream>>>(
        hbf, attnw_bf + l * 49152, absb + l * 384, qkvc, 131072, 384, 128);
    attn_mfma<<<1024, 512, 0, stream>>>(qkvc, obf);
    oproj_ln<<<1024, 256, 0, stream>>>(obf, outwA + l * 16384, out_b + l * 128,
                                       hbf, n1_g + l * 128, n1_b + l * 128);
    ffn_reg<<<1024, 256, 0, stream>>>(hbf, w1A + l * 65536, ff1_b + l * 512,
                                      w2A + l * 65536, ff2_b + l * 128,
                                      n2_g + l * 128, n2_b + l * 128);
  }

  vocab_entropy<<<1024, 256, 0, stream>>>(hbf, projA, proj_b, entb);
  avg_entropy_kernel<<<512, 64, 0, stream>>>(entb, (float*)d_out);
  seg_kernel<<<1, 512, 0, stream>>>((float*)d_out);
}